// Round 8
// baseline (678.071 us; speedup 1.0000x reference)
//
#include <hip/hip_runtime.h>
#include <math.h>

#define N_NODES 10000
#define N_EDGES 160000
#define DIM 512
#define HDIM 256
#define EDIM 16
#define BN_EPS 1e-5f
#define L2E 1.4426950408889634f
#define LN2 0.6931471805599453f

typedef unsigned short ushort_t;
typedef unsigned int uint_t;
typedef __attribute__((ext_vector_type(8))) short bf16x8;
typedef __attribute__((ext_vector_type(4))) float f32x4;
typedef __attribute__((ext_vector_type(2))) _Float16 half2_t;

// ---------------- helpers ----------------
__device__ __forceinline__ ushort_t f2bf(float x) {
    uint_t u = __float_as_uint(x);
    uint_t r = (u + 0x7FFF + ((u >> 16) & 1)) >> 16;  // RNE
    return (ushort_t)r;
}
__device__ __forceinline__ float bf2f(ushort_t h) {
    return __uint_as_float(((uint_t)h) << 16);
}
__device__ __forceinline__ float bflo(uint_t u) {
    return __uint_as_float(u << 16);
}
__device__ __forceinline__ float bfhi(uint_t u) {
    return __uint_as_float(u & 0xffff0000u);
}
__device__ __forceinline__ void gld16(const void* g, void* l) {
    __builtin_amdgcn_global_load_lds(
        (const __attribute__((address_space(1))) unsigned int*)g,
        (__attribute__((address_space(3))) unsigned int*)l, 16, 0, 0);
}
__device__ __forceinline__ half2_t u2h(uint_t u) {
    return __builtin_bit_cast(half2_t, u);
}
__device__ __forceinline__ uint_t pk_f16(float a, float b) {
    return __builtin_bit_cast(uint_t, __builtin_amdgcn_cvt_pkrtz(a, b));
}
__device__ __forceinline__ void swz(int lid, int gx, int gy, int& bx, int& by) {
    int per = gy * 8;
    int grp = lid / per;
    int rem = lid - grp * per;
    int gsz = min(8, gx - grp * 8);
    by = rem / gsz;
    bx = grp * 8 + (rem - by * gsz);
}

// ---------------- CSR build ----------------
__global__ void k_hist(const int* __restrict__ dst, int* __restrict__ cnt) {
    int e = blockIdx.x * blockDim.x + threadIdx.x;
    if (e < N_EDGES) atomicAdd(&cnt[dst[e]], 1);
}

__global__ __launch_bounds__(1024) void k_scan(int* __restrict__ offs, float* __restrict__ dinv) {
    __shared__ int wsum[16];
    __shared__ int carryS;
    int t = threadIdx.x, lane = t & 63, wv = t >> 6;
    if (t == 0) carryS = 0;
    __syncthreads();
    for (int base = 0; base < N_NODES; base += 1024) {
        int idx = base + t;
        int v = (idx < N_NODES) ? offs[idx] : 0;
        if (idx < N_NODES) dinv[idx] = rsqrtf((float)v + 1.0f);
        int s = v;
#pragma unroll
        for (int off = 1; off < 64; off <<= 1) {
            int u = __shfl_up(s, off, 64);
            if (lane >= off) s += u;
        }
        if (lane == 63) wsum[wv] = s;
        __syncthreads();
        int carry = carryS;
        if (wv == 0) {
            int w = (lane < 16) ? wsum[lane] : 0;
#pragma unroll
            for (int off = 1; off < 16; off <<= 1) {
                int u = __shfl_up(w, off, 64);
                if (lane >= off) w += u;
            }
            if (lane < 16) wsum[lane] = w;
        }
        __syncthreads();
        int wbase = (wv == 0) ? 0 : wsum[wv - 1];
        if (idx < N_NODES) offs[idx] = carry + wbase + s - v;
        int total = wsum[15];
        __syncthreads();
        if (t == 0) carryS = carry + total;
        __syncthreads();
    }
    if (t == 0) offs[N_NODES] = carryS;
}

__global__ void k_scatter(const int* __restrict__ srcv, const int* __restrict__ dstv,
                          const float* __restrict__ ea,
                          const int* __restrict__ offs, const float* __restrict__ dinv,
                          int* __restrict__ cursor,
                          int* __restrict__ srcArr, float* __restrict__ dinvArr,
                          uint_t* __restrict__ eaP) {
    int e = blockIdx.x * blockDim.x + threadIdx.x;
    if (e >= N_EDGES) return;
    int d = dstv[e];
    int p = offs[d] + atomicAdd(&cursor[d], 1);
    int s = srcv[e];
    srcArr[p] = s;
    dinvArr[p] = dinv[s];
    const float* er = ea + (size_t)e * EDIM;
    uint_t pk[8];
#pragma unroll
    for (int k2 = 0; k2 < 8; k2++) pk[k2] = pk_f16(er[2 * k2], er[2 * k2 + 1]);
    uint_t* q = eaP + (size_t)p * 8;
    *(uint4*)q = *(uint4*)&pk[0];
    *(uint4*)(q + 4) = *(uint4*)&pk[4];
}

// ---------------- tiled transpose-convert for weights (coalesced) ----------------
__global__ __launch_bounds__(256) void k_cvtW(
    const float* __restrict__ Wf0, const float* __restrict__ Ws0,
    const float* __restrict__ Wf1, const float* __restrict__ Ws1,
    const float* __restrict__ g3W, const float* __restrict__ g4W,
    const float* __restrict__ d1W,
    ushort_t* __restrict__ W2cg0, ushort_t* __restrict__ W2cg1,
    ushort_t* __restrict__ W2g3, ushort_t* __restrict__ W2g4,
    ushort_t* __restrict__ W2d1)
{
    __shared__ ushort_t tle[64][72];
    int b = blockIdx.x, t = threadIdx.x;
    const float* src; int ldw, kin0, cin0, ldk, cout0, kout0; ushort_t* out; float scale;
    if (b < 512) {
        int layer = b >> 8, tt = b & 255;
        int g = tt >> 6, rem = tt & 63;
        int ct = rem >> 3, kt = rem & 7;
        const float* Wf = layer ? Wf1 : Wf0;
        const float* Ws = layer ? Ws1 : Ws0;
        src = (g & 1) ? Ws : Wf;
        ldw = 512; kin0 = ((g & 2) ? 512 : 0) + kt * 64; cin0 = ct * 64;
        out = layer ? W2cg1 : W2cg0; ldk = 512;
        cout0 = g * 512 + ct * 64; kout0 = kt * 64;
        scale = L2E;  // gate weights pre-scaled to exp2 domain
    } else if (b < 544) {
        int tt = b - 512; int ct = tt >> 3, kt = tt & 7;
        src = g3W; ldw = 256; kin0 = kt * 64; cin0 = ct * 64;
        out = W2g3; ldk = 512; cout0 = ct * 64; kout0 = kt * 64; scale = 1.f;
    } else if (b < 560) {
        int tt = b - 544; int ct = tt >> 2, kt = tt & 3;
        src = g4W; ldw = 256; kin0 = kt * 64; cin0 = ct * 64;
        out = W2g4; ldk = 256; cout0 = ct * 64; kout0 = kt * 64; scale = 1.f;
    } else {
        int tt = b - 560; int ct = tt >> 2, kt = tt & 3;
        src = d1W; ldw = 512; kin0 = kt * 64; cin0 = ct * 64;
        out = W2d1; ldk = 256; cout0 = ct * 64; kout0 = kt * 64; scale = 1.f;
    }
    int c = t & 63;
    int k4 = t >> 6;
#pragma unroll
    for (int i = 0; i < 16; i++) {
        int k = k4 * 16 + i;
        tle[k][c] = f2bf(src[(size_t)(kin0 + k) * ldw + cin0 + c] * scale);
    }
    __syncthreads();
    int cl = t >> 2, kq = t & 3;
    ushort_t tmp[16];
#pragma unroll
    for (int j = 0; j < 16; j++) tmp[j] = tle[kq * 16 + j][cl];
    ushort_t* dst = out + (size_t)(cout0 + cl) * ldk + kout0 + kq * 16;
    *(uint4*)dst = *(uint4*)&tmp[0];
    *(uint4*)(dst + 8) = *(uint4*)&tmp[8];
}

// ---------------- mega prep: WEP + goalvec + cvtA ----------------
#define MP_WEP   32
#define MP_GV    40
#define MP_END   20040

__global__ __launch_bounds__(256) void k_megaprep(
    const float* __restrict__ x, const float* __restrict__ goal,
    const float* __restrict__ Wf0, const float* __restrict__ Ws0,
    const float* __restrict__ Wf1, const float* __restrict__ Ws1,
    const float* __restrict__ d1W, const float* __restrict__ d1b,
    ushort_t* __restrict__ A2, uint_t* __restrict__ WEP, float* __restrict__ cgv)
{
    int b = blockIdx.x, t = threadIdx.x;
    if (b < MP_WEP) {
        int layer = b >> 4, blk = b & 15;
        int idx = blk * 256 + t;
        int c = idx >> 3, k2 = idx & 7;
        const float* Wf = (layer ? Wf1 : Wf0) + 1024 * 512;
        const float* Ws = (layer ? Ws1 : Ws0) + 1024 * 512;
        uint_t* WEPf = WEP + layer * 8192;
        uint_t* WEPs = WEPf + 4096;
        WEPf[c * 8 + k2] = pk_f16(Wf[(2 * k2) * 512 + c] * L2E, Wf[(2 * k2 + 1) * 512 + c] * L2E);
        WEPs[c * 8 + k2] = pk_f16(Ws[(2 * k2) * 512 + c] * L2E, Ws[(2 * k2 + 1) * 512 + c] * L2E);
    } else if (b < MP_GV) {
        __shared__ float red[256];
        int bb = b - MP_WEP;
        int c = bb * 64 + (t & 63);
        int slice = t >> 6;
        float acc = 0.f;
        for (int i = 0; i < 128; i++) {
            int k = slice * 128 + i;
            acc += goal[k] * d1W[(size_t)(256 + k) * 512 + c];
        }
        red[t] = acc;
        __syncthreads();
        if (t < 128) red[t] += red[t + 128];
        __syncthreads();
        if (t < 64) cgv[c] = red[t] + red[t + 64] + d1b[c];
    } else {
        int idx = (b - MP_GV) * 256 + t;
        if (idx < N_NODES * 512) {
            int m = idx >> 9, k = idx & 511;
            float v = x[idx];
            ushort_t hi = f2bf(v);
            ushort_t lo = f2bf(v - bf2f(hi));
            size_t rb = (size_t)m * 1024;
            A2[rb + k] = hi;
            A2[rb + 512 + k] = lo;
        }
    }
}

// ---------------- bf16 MFMA GEMM, BM=128, BK=64, B k-wrap (W2t stores KH) ----------------
__global__ __launch_bounds__(256) void k_gemm3(
    const ushort_t* __restrict__ A2, int lda, int KH, int M,
    const ushort_t* __restrict__ W2t,
    float* __restrict__ outF, ushort_t* __restrict__ outQ,
    const float* __restrict__ bias, int mode, int ldc, int gx, int gy)
{
    __shared__ ushort_t As[128 * 64];
    __shared__ ushort_t Bs[128 * 64];
    const int Ktot = 2 * KH;
    int tid = threadIdx.x;
    int lane = tid & 63, w = tid >> 6;
    int wm = w & 1, wn = w >> 1;
    int lrow = lane & 15, quad = lane >> 4;
    int bx, by;
    swz(blockIdx.x, gx, gy, bx, by);
    int row0 = bx * 128, col0 = by * 128;

    f32x4 acc[4][4] = {};

    const ushort_t* ArG[4]; ushort_t* ArL[4];
    const ushort_t* BrG[4]; ushort_t* BrL[4];
#pragma unroll
    for (int p = 0; p < 4; p++) {
        int s = tid + 256 * p;
        int r = s >> 3, k8p = s & 7;
        int k8l = k8p ^ (r & 7);
        int gra = row0 + r; if (gra >= M) gra = M - 1;
        ArG[p] = A2 + (size_t)gra * lda + k8l * 8;
        ArL[p] = As + s * 8;
        BrG[p] = W2t + (size_t)(col0 + r) * KH + k8l * 8;
        BrL[p] = Bs + s * 8;
    }
    const ushort_t* afp[2][4];
    const ushort_t* bfp[2][4];
#pragma unroll
    for (int sl = 0; sl < 2; sl++)
#pragma unroll
        for (int mt = 0; mt < 4; mt++) {
            int r = wm * 64 + mt * 16 + lrow;
            afp[sl][mt] = As + (r * 8 + ((sl * 4 + quad) ^ (r & 7))) * 8;
            int c = wn * 64 + mt * 16 + lrow;
            bfp[sl][mt] = Bs + (c * 8 + ((sl * 4 + quad) ^ (c & 7))) * 8;
        }

    for (int k0 = 0; k0 < Ktot; k0 += 64) {
        int bk0 = k0 & (KH - 1);
        __syncthreads();
#pragma unroll
        for (int p = 0; p < 4; p++) {
            gld16(ArG[p] + k0, ArL[p]);
            gld16(BrG[p] + bk0, BrL[p]);
        }
        __syncthreads();
#pragma unroll
        for (int sl = 0; sl < 2; sl++) {
            bf16x8 af[4], bff[4];
#pragma unroll
            for (int i = 0; i < 4; i++) {
                af[i]  = *(const bf16x8*)afp[sl][i];
                bff[i] = *(const bf16x8*)bfp[sl][i];
            }
#pragma unroll
            for (int mt = 0; mt < 4; mt++)
#pragma unroll
                for (int nt = 0; nt < 4; nt++)
                    acc[mt][nt] = __builtin_amdgcn_mfma_f32_16x16x32_bf16(
                        af[mt], bff[nt], acc[mt][nt], 0, 0, 0);
        }
    }

#pragma unroll
    for (int mt = 0; mt < 4; mt++) {
#pragma unroll
        for (int nt = 0; nt < 4; nt++) {
            int gcol = col0 + wn * 64 + nt * 16 + lrow;
#pragma unroll
            for (int r = 0; r < 4; r++) {
                int grow = row0 + wm * 64 + mt * 16 + quad * 4 + r;
                if (grow >= M) continue;
                float v = acc[mt][nt][r];
                if (mode == 1) {
                    if (gcol < 1024) {
                        outF[(size_t)grow * 1024 + gcol] = v;
                    } else {
                        int c = gcol - 1024;
                        int grp = c >> 9, cc = c & 511;
                        int pos = (cc >> 1) * 4 + grp * 2 + (cc & 1);
                        outQ[(size_t)grow * 1024 + pos] = f2bf(v);
                    }
                } else if (mode == 2) {
                    outF[(size_t)grow * ldc + gcol] = fmaxf(v + bias[gcol], 0.f);
                } else {
                    outQ[(size_t)grow * ldc + gcol] = f2bf(v);
                }
            }
        }
    }
}

// ---------------- bf16 MFMA GEMM, BM=64, BK=64 ----------------
__global__ __launch_bounds__(256) void k_gemm64(
    const ushort_t* __restrict__ A2, int lda, int KH, int M,
    const ushort_t* __restrict__ W2t,
    float* __restrict__ outF, ushort_t* __restrict__ outQ,
    const float* __restrict__ bias, int mode, int ldc, int gx, int gy)
{
    __shared__ ushort_t As[64 * 64];
    __shared__ ushort_t Bs[128 * 64];
    const int Ktot = 2 * KH;
    int tid = threadIdx.x;
    int lane = tid & 63, w = tid >> 6;
    int lrow = lane & 15, quad = lane >> 4;
    int bx, by;
    swz(blockIdx.x, gx, gy, bx, by);
    int row0 = bx * 64, col0 = by * 128;

    f32x4 acc[4][2] = {};

    const ushort_t* ArG[2]; ushort_t* ArL[2];
    const ushort_t* BrG[4]; ushort_t* BrL[4];
#pragma unroll
    for (int p = 0; p < 2; p++) {
        int s = tid + 256 * p;
        int r = s >> 3, k8p = s & 7;
        int k8l = k8p ^ (r & 7);
        int gra = row0 + r; if (gra >= M) gra = M - 1;
        ArG[p] = A2 + (size_t)gra * lda + k8l * 8;
        ArL[p] = As + s * 8;
    }
#pragma unroll
    for (int p = 0; p < 4; p++) {
        int s = tid + 256 * p;
        int r = s >> 3, k8p = s & 7;
        int k8l = k8p ^ (r & 7);
        BrG[p] = W2t + (size_t)(col0 + r) * KH + k8l * 8;
        BrL[p] = Bs + s * 8;
    }
    const ushort_t* afp[2][4];
    const ushort_t* bfp[2][2];
#pragma unroll
    for (int sl = 0; sl < 2; sl++) {
#pragma unroll
        for (int mt = 0; mt < 4; mt++) {
            int r = mt * 16 + lrow;
            afp[sl][mt] = As + (r * 8 + ((sl * 4 + quad) ^ (r & 7))) * 8;
        }
#pragma unroll
        for (int nt = 0; nt < 2; nt++) {
            int c = w * 32 + nt * 16 + lrow;
            bfp[sl][nt] = Bs + (c * 8 + ((sl * 4 + quad) ^ (c & 7))) * 8;
        }
    }

    for (int k0 = 0; k0 < Ktot; k0 += 64) {
        int bk0 = k0 & (KH - 1);
        __syncthreads();
        gld16(ArG[0] + k0, ArL[0]);
        gld16(ArG[1] + k0, ArL[1]);
#pragma unroll
        for (int p = 0; p < 4; p++) gld16(BrG[p] + bk0, BrL[p]);
        __syncthreads();
#pragma unroll
        for (int sl = 0; sl < 2; sl++) {
            bf16x8 af[4], bff[2];
#pragma unroll
            for (int i = 0; i < 4; i++) af[i] = *(const bf16x8*)afp[sl][i];
#pragma unroll
            for (int i = 0; i < 2; i++) bff[i] = *(const bf16x8*)bfp[sl][i];
#pragma unroll
            for (int mt = 0; mt < 4; mt++)
#pragma unroll
                for (int nt = 0; nt < 2; nt++)
                    acc[mt][nt] = __builtin_amdgcn_mfma_f32_16x16x32_bf16(
                        af[mt], bff[nt], acc[mt][nt], 0, 0, 0);
        }
    }

#pragma unroll
    for (int mt = 0; mt < 4; mt++) {
#pragma unroll
        for (int nt = 0; nt < 2; nt++) {
            int gcol = col0 + w * 32 + nt * 16 + lrow;
#pragma unroll
            for (int r = 0; r < 4; r++) {
                int grow = row0 + mt * 16 + quad * 4 + r;
                if (grow >= M) continue;
                float v = acc[mt][nt][r];
                if (mode == 2) outF[(size_t)grow * ldc + gcol] = fmaxf(v + bias[gcol], 0.f);
                else outQ[(size_t)grow * ldc + gcol] = f2bf(v);
            }
        }
    }
}

// ---------------- CGConv aggregation (exp2-domain gates) ----------------
__global__ __launch_bounds__(256) void k_cg_aggr(
    const float* __restrict__ xin, const float* __restrict__ P,
    const ushort_t* __restrict__ Qi,
    const uint_t* __restrict__ WEPf, const uint_t* __restrict__ WEPs,
    const float* __restrict__ bfv, const float* __restrict__ bsv,
    const float* __restrict__ gamma, const float* __restrict__ beta,
    const float* __restrict__ mean, const float* __restrict__ var,
    const int* __restrict__ offs, const int* __restrict__ srcArr,
    const uint_t* __restrict__ eaP,
    float* __restrict__ xout, ushort_t* __restrict__ A2out)
{
    int i = blockIdx.x;
    int t = threadIdx.x;
    int c0 = 2 * t;
    uint_t wfp[2][8], wsp[2][8];
    {
        const uint_t* pf8 = WEPf + c0 * 8;
        const uint_t* ps8 = WEPs + c0 * 8;
        *(uint4*)&wfp[0][0] = *(const uint4*)(pf8 + 0);
        *(uint4*)&wfp[0][4] = *(const uint4*)(pf8 + 4);
        *(uint4*)&wfp[1][0] = *(const uint4*)(pf8 + 8);
        *(uint4*)&wfp[1][4] = *(const uint4*)(pf8 + 12);
        *(uint4*)&wsp[0][0] = *(const uint4*)(ps8 + 0);
        *(uint4*)&wsp[0][4] = *(const uint4*)(ps8 + 4);
        *(uint4*)&wsp[1][0] = *(const uint4*)(ps8 + 8);
        *(uint4*)&wsp[1][4] = *(const uint4*)(ps8 + 12);
    }
    float2 pf = *(const float2*)&P[(size_t)i * 1024 + c0];
    float2 ps = *(const float2*)&P[(size_t)i * 1024 + 512 + c0];
    float2 bf2 = *(const float2*)&bfv[c0];
    float2 bs2 = *(const float2*)&bsv[c0];
    pf.x = fmaf(bf2.x, L2E, pf.x); pf.y = fmaf(bf2.y, L2E, pf.y);
    ps.x = fmaf(bs2.x, L2E, ps.x); ps.y = fmaf(bs2.y, L2E, ps.y);
    float acc0 = 0.f, acc1 = 0.f;
    int e0 = offs[i], e1 = offs[i + 1];
    __shared__ uint_t sEaP[16][8];
    __shared__ int sSrc[18];
    const ushort_t* Qbase = Qi + 4 * t;
    for (int base = e0; base < e1; base += 16) {
        int g = min(16, e1 - base);
        __syncthreads();
        if (t < 18) {
            int s = 0;
            if (t < g) s = srcArr[base + t];
            sSrc[t] = s;
        } else if (t >= 32 && t < 160) {
            int tt = t - 32;
            int j = tt >> 3, k2 = tt & 7;
            if (j < g) sEaP[j][k2] = eaP[(size_t)(base + j) * 8 + k2];
        }
        __syncthreads();
        uint2 q0 = *(const uint2*)(Qbase + ((size_t)sSrc[0] << 10));
        uint2 q1 = *(const uint2*)(Qbase + ((size_t)sSrc[1] << 10));
        for (int j = 0; j < g; j++) {
            uint2 qn = *(const uint2*)(Qbase + ((size_t)sSrc[j + 2] << 10));
            uint4 eA = *(const uint4*)&sEaP[j][0];
            uint4 eB = *(const uint4*)&sEaP[j][4];
            float gf0 = pf.x + bflo(q0.x), gf1 = pf.y + bfhi(q0.x);
            float gs0 = ps.x + bflo(q0.y), gs1 = ps.y + bfhi(q0.y);
            uint_t ek[8] = {eA.x, eA.y, eA.z, eA.w, eB.x, eB.y, eB.z, eB.w};
#pragma unroll
            for (int k = 0; k < 8; k++) {
                half2_t e2 = u2h(ek[k]);
                gf0 = __builtin_amdgcn_fdot2(e2, u2h(wfp[0][k]), gf0, false);
                gf1 = __builtin_amdgcn_fdot2(e2, u2h(wfp[1][k]), gf1, false);
                gs0 = __builtin_amdgcn_fdot2(e2, u2h(wsp[0][k]), gs0, false);
                gs1 = __builtin_amdgcn_fdot2(e2, u2h(wsp[1][k]), gs1, false);
            }
            // exp2-domain: g* are true-gate * log2(e)
            float sg0 = __builtin_amdgcn_rcpf(1.f + exp2f(-gf0));
            float sg1 = __builtin_amdgcn_rcpf(1.f + exp2f(-gf1));
            float sp0 = fmaxf(gs0, 0.f) + log2f(1.f + exp2f(-fabsf(gs0)));
            float sp1 = fmaxf(gs1, 0.f) + log2f(1.f + exp2f(-fabsf(gs1)));
            acc0 = fmaf(sg0, sp0, acc0);
            acc1 = fmaf(sg1, sp1, acc1);
            q0 = q1; q1 = qn;
        }
    }
    acc0 *= LN2;  // softplus ln2 factor folded out of the edge sum
    acc1 *= LN2;
    size_t ib = (size_t)i * DIM;
    float2 mn = *(const float2*)&mean[c0];
    float2 vr = *(const float2*)&var[c0];
    float2 gm = *(const float2*)&gamma[c0];
    float2 bt = *(const float2*)&beta[c0];
    float2 xi = *(const float2*)&xin[ib + c0];
    float bn0 = (acc0 - mn.x) * rsqrtf(vr.x + BN_EPS) * gm.x + bt.x;
    float bn1 = (acc1 - mn.y) * rsqrtf(vr.y + BN_EPS) * gm.y + bt.y;
    float o0 = fmaxf(xi.x + bn0, 0.f);
    float o1 = fmaxf(xi.y + bn1, 0.f);
    *(float2*)&xout[ib + c0] = make_float2(o0, o1);
    ushort_t h0 = f2bf(o0), h1 = f2bf(o1);
    ushort_t l0 = f2bf(o0 - bf2f(h0)), l1 = f2bf(o1 - bf2f(h1));
    *(uint_t*)(A2out + (size_t)i * 1024 + c0)       = (uint_t)h0 | ((uint_t)h1 << 16);
    *(uint_t*)(A2out + (size_t)i * 1024 + 512 + c0) = (uint_t)l0 | ((uint_t)l1 << 16);
}

// ---------------- GCN aggregation ----------------
__global__ __launch_bounds__(128) void k_gcn_aggr(
    const ushort_t* __restrict__ h, const float* __restrict__ dinv,
    const float* __restrict__ bias,
    const int* __restrict__ offs, const int* __restrict__ srcArr,
    const float* __restrict__ dinvArr, ushort_t* __restrict__ A2out)
{
    int i = blockIdx.x;
    int t = threadIdx.x;
    int c0 = 2 * t;
    float acc0 = 0.f, acc1 = 0.f;
    int e0 = offs[i], e1 = offs[i + 1];
    __shared__ int sS[20];
    __shared__ float sD[20];
    for (int base = e0; base < e1; base += 16) {
        int g = min(16, e1 - base);
        __syncthreads();
        if (t < 20) {
            bool ok = (t < g);
            sS[t] = ok ? srcArr[base + t] : 0;
            sD[t] = ok ? dinvArr[base + t] : 0.f;
        }
        __syncthreads();
        uint_t q0 = *(const uint_t*)(h + (size_t)sS[0] * HDIM + c0);
        uint_t q1 = *(const uint_t*)(h + (size_t)sS[1] * HDIM + c0);
        uint_t q2 = *(const uint_t*)(h + (size_t)sS[2] * HDIM + c0);
        uint_t q3 = *(const uint_t*)(h + (size_t)sS[3] * HDIM + c0);
        for (int j = 0; j < g; j++) {
            uint_t qn = *(const uint_t*)(h + (size_t)sS[j + 4] * HDIM + c0);
            acc0 += sD[j] * bflo(q0);
            acc1 += sD[j] * bfhi(q0);
            q0 = q1; q1 = q2; q2 = q3; q3 = qn;
        }
    }
    float di = dinv[i];
    uint_t qi = *(const uint_t*)(h + (size_t)i * HDIM + c0);
    float2 b2 = *(const float2*)&bias[c0];
    float o0 = fmaxf(di * acc0 + di * di * bflo(qi) + b2.x, 0.f);
    float o1 = fmaxf(di * acc1 + di * di * bfhi(qi) + b2.y, 0.f);
    ushort_t h0 = f2bf(o0), h1 = f2bf(o1);
    ushort_t l0 = f2bf(o0 - bf2f(h0)), l1 = f2bf(o1 - bf2f(h1));
    *(uint_t*)(A2out + (size_t)i * 512 + c0)       = (uint_t)h0 | ((uint_t)h1 << 16);
    *(uint_t*)(A2out + (size_t)i * 512 + 256 + c0) = (uint_t)l0 | ((uint_t)l1 << 16);
}

// ---------------- final dot ----------------
__global__ __launch_bounds__(256) void k_final(const float* __restrict__ hd,
                                               const float* __restrict__ w2,
                                               const float* __restrict__ b2,
                                               float* __restrict__ out) {
    int wave = threadIdx.x >> 6, lane = threadIdx.x & 63;
    int i = blockIdx.x * 4 + wave;
    if (i >= N_NODES) return;
    const float* r = hd + (size_t)i * DIM;
    float acc = 0.f;
#pragma unroll
    for (int q = 0; q < 8; q++) acc += r[lane + 64 * q] * w2[lane + 64 * q];
#pragma unroll
    for (int off = 32; off > 0; off >>= 1) acc += __shfl_down(acc, off, 64);
    if (lane == 0) out[i] = acc + b2[0];
}

// ---------------- launch ----------------
extern "C" void kernel_launch(void* const* d_in, const int* in_sizes, int n_in,
                              void* d_out, int out_size, void* d_ws, size_t ws_size,
                              hipStream_t stream) {
    (void)in_sizes; (void)n_in; (void)out_size; (void)ws_size;
    const float* x      = (const float*)d_in[0];
    const float* ea     = (const float*)d_in[1];
    const float* goal   = (const float*)d_in[2];
    const float* cgWf[2] = {(const float*)d_in[3],  (const float*)d_in[11]};
    const float* cgbf[2] = {(const float*)d_in[4],  (const float*)d_in[12]};
    const float* cgWs[2] = {(const float*)d_in[5],  (const float*)d_in[13]};
    const float* cgbs[2] = {(const float*)d_in[6],  (const float*)d_in[14]};
    const float* cggm[2] = {(const float*)d_in[7],  (const float*)d_in[15]};
    const float* cgbt[2] = {(const float*)d_in[8],  (const float*)d_in[16]};
    const float* cgmn[2] = {(const float*)d_in[9],  (const float*)d_in[17]};
    const float* cgvr[2] = {(const float*)d_in[10], (const float*)d_in[18]};
    const float* gcn3_W = (const float*)d_in[19];
    const float* gcn3_b = (const float*)d_in[20];
    const float* gcn4_W = (const float*)d_in[21];
    const float* gcn4_b = (const float*)d_in[22];
    const float* d1_W   = (const float*)d_in[23];
    const float* d1_b   = (const float*)d_in[24];
    const float* d2_W   = (const float*)d_in[25];
    const float* d2_b   = (const float*)d_in[26];
    const int*   eidx   = (const int*)d_in[27];
    const int*   srcv   = eidx;
    const int*   dstv   = eidx + N_EDGES;
    float* outp = (float*)d_out;

    // ---- workspace layout (~113 MB) ----
    char* w = (char*)d_ws;
    float*    Pbuf  = (float*)w;                      w += (size_t)N_NODES * 1024 * 4;
    ushort_t* Qbuf  = (ushort_t*)w;                   w += (size_t)N_NODES * 1024 * 2;
    float*    xB    = (float*)w;                      w += (size_t)N_NODES * 512 * 4;
    ushort_t* A2    = (ushort_t*)w;                   w += (size_t)N_NODES * 1024 * 2;
    ushort_t* W2cg0 = (ushort_t*)w;                   w += (size_t)2048 * 512 * 2;
    ushort_t* W2cg1 = (ushort_t*)w;                   w += (size_t)2048 * 512 * 2;
    ushort_t* W2g3  = (ushort_t*)w;                   w += (size_t)256 * 512 * 2;
    ushort_t* W2g4  = (ushort_t*)w;                   w += (size_t)256 * 256 * 2;
    ushort_t* W2d1  = (ushort_t*)w;                   w += (size_t)512 * 256 * 2;
    uint_t*   eaP   = (uint_t*)w;                     w += (size_t)N_EDGES * 8 * 4;
    uint_t*   WEP   = (uint_t*)w;                     w += 16384 * 4;
    float*    cgv   = (float*)w;                      w += 512 * 4;
    int*      srcArr  = (int*)w;                      w += N_EDGES * 4;
    float*    dinvArr = (float*)w;                    w += N_EDGES * 4;
    int*      offs    = (int*)w;                      w += (N_NODES + 1) * 4;
    int*      cursor  = (int*)w;                      w += N_NODES * 4;
    float*    dinv    = (float*)w;                    w += N_NODES * 4;
    uint_t* WEPf[2] = {WEP, WEP + 8192};
    uint_t* WEPs[2] = {WEP + 4096, WEP + 12288};
    ushort_t* h3 = (ushort_t*)Pbuf;
    ushort_t* h4 = h3 + (size_t)N_NODES * HDIM;
    float*    hd = (float*)Qbuf;

    // ---- prep ----
    k_cvtW<<<592, 256, 0, stream>>>(cgWf[0], cgWs[0], cgWf[1], cgWs[1],
                                    gcn3_W, gcn4_W, d1_W,
                                    W2cg0, W2cg1, W2g3, W2g4, W2d1);
    k_megaprep<<<MP_END, 256, 0, stream>>>(x, goal,
        cgWf[0], cgWs[0], cgWf[1], cgWs[1], d1_W, d1_b, A2, WEP, cgv);

    // ---- CSR build ----
    hipMemsetAsync(offs, 0, (N_NODES + 1) * sizeof(int), stream);
    hipMemsetAsync(cursor, 0, N_NODES * sizeof(int), stream);
    k_hist<<<(N_EDGES + 255) / 256, 256, 0, stream>>>(dstv, offs);
    k_scan<<<1, 1024, 0, stream>>>(offs, dinv);
    k_scatter<<<(N_EDGES + 255) / 256, 256, 0, stream>>>(srcv, dstv, ea, offs, dinv,
                                                         cursor, srcArr, dinvArr, eaP);

    // ---- CG layer 1 ----
    k_gemm3<<<79 * 16, 256, 0, stream>>>(A2, 1024, 512, N_NODES, W2cg0,
                                         Pbuf, Qbuf, nullptr, 1, 0, 79, 16);
    k_cg_aggr<<<N_NODES, 256, 0, stream>>>(x, Pbuf, Qbuf, WEPf[0], WEPs[0],
                                           cgbf[0], cgbs[0],
                                           cggm[0], cgbt[0], cgmn[0], cgvr[0],
                                           offs, srcArr, eaP, xB, A2);
    // ---- CG layer 2 ----
    k_gemm3<<<79 * 16, 256, 0, stream>>>(A2, 1024, 512, N_NODES, W2cg1,
                                         Pbuf, Qbuf, nullptr, 1, 0, 79, 16);
    k_cg_aggr<<<N_NODES, 256, 0, stream>>>(xB, Pbuf, Qbuf, WEPf[1], WEPs[1],
                                           cgbf[1], cgbs[1],
                                           cggm[1], cgbt[1], cgmn[1], cgvr[1],
                                           offs, srcArr, eaP, xB, A2);

    // ---- GCN 3: 512 -> 256 ----
    k_gemm64<<<157 * 2, 256, 0, stream>>>(A2, 1024, 512, N_NODES, W2g3,
                                          nullptr, h3, nullptr, 3, HDIM, 157, 2);
    k_gcn_aggr<<<N_NODES, 128, 0, stream>>>(h3, dinv, gcn3_b, offs, srcArr, dinvArr, A2);

    // ---- GCN 4: 256 -> 256 ----
    k_gemm64<<<157 * 2, 256, 0, stream>>>(A2, 512, 256, N_NODES, W2g4,
                                          nullptr, h4, nullptr, 3, HDIM, 157, 2);
    k_gcn_aggr<<<N_NODES, 128, 0, stream>>>(h4, dinv, gcn4_b, offs, srcArr, dinvArr, A2);

    // ---- dense head ----
    k_gemm64<<<157 * 4, 256, 0, stream>>>(A2, 512, 256, N_NODES, W2d1,
                                          hd, nullptr, cgv, 2, DIM, 157, 4);
    k_final<<<(N_NODES + 3) / 4, 256, 0, stream>>>(hd, d2_W, d2_b, outp);
}

// Round 9
// 629.526 us; speedup vs baseline: 1.0771x; 1.0771x over previous
//
#include <hip/hip_runtime.h>
#include <math.h>

#define N_NODES 10000
#define N_EDGES 160000
#define DIM 512
#define HDIM 256
#define EDIM 16
#define BN_EPS 1e-5f
#define L2E 1.4426950408889634f
#define LN2 0.6931471805599453f

typedef unsigned short ushort_t;
typedef unsigned int uint_t;
typedef __attribute__((ext_vector_type(8))) short bf16x8;
typedef __attribute__((ext_vector_type(4))) float f32x4;
typedef __attribute__((ext_vector_type(2))) _Float16 half2_t;

// ---------------- helpers ----------------
__device__ __forceinline__ ushort_t f2bf(float x) {
    uint_t u = __float_as_uint(x);
    uint_t r = (u + 0x7FFF + ((u >> 16) & 1)) >> 16;  // RNE
    return (ushort_t)r;
}
__device__ __forceinline__ float bf2f(ushort_t h) {
    return __uint_as_float(((uint_t)h) << 16);
}
__device__ __forceinline__ float bflo(uint_t u) {
    return __uint_as_float(u << 16);
}
__device__ __forceinline__ float bfhi(uint_t u) {
    return __uint_as_float(u & 0xffff0000u);
}
__device__ __forceinline__ void gld16(const void* g, void* l) {
    __builtin_amdgcn_global_load_lds(
        (const __attribute__((address_space(1))) unsigned int*)g,
        (__attribute__((address_space(3))) unsigned int*)l, 16, 0, 0);
}
__device__ __forceinline__ half2_t u2h(uint_t u) {
    return __builtin_bit_cast(half2_t, u);
}
__device__ __forceinline__ uint_t pk_f16(float a, float b) {
    return __builtin_bit_cast(uint_t, __builtin_amdgcn_cvt_pkrtz(a, b));
}
// raw HW transcendentals: v_exp_f32 (2^x), v_log_f32 (log2 x) — no libm precision path
__device__ __forceinline__ float fexp2(float x) {
#if __has_builtin(__builtin_amdgcn_exp2f)
    return __builtin_amdgcn_exp2f(x);
#else
    return __expf(x * LN2);
#endif
}
__device__ __forceinline__ float flog2(float x) {
#if __has_builtin(__builtin_amdgcn_logf)
    return __builtin_amdgcn_logf(x);
#else
    return __logf(x) * L2E;
#endif
}
__device__ __forceinline__ void swz(int lid, int gx, int gy, int& bx, int& by) {
    int per = gy * 8;
    int grp = lid / per;
    int rem = lid - grp * per;
    int gsz = min(8, gx - grp * 8);
    by = rem / gsz;
    bx = grp * 8 + (rem - by * gsz);
}

// ---------------- CSR build ----------------
__global__ void k_hist(const int* __restrict__ dst, int* __restrict__ cnt) {
    int e = blockIdx.x * blockDim.x + threadIdx.x;
    if (e < N_EDGES) atomicAdd(&cnt[dst[e]], 1);
}

__global__ __launch_bounds__(1024) void k_scan(int* __restrict__ offs, float* __restrict__ dinv) {
    __shared__ int wsum[16];
    __shared__ int carryS;
    int t = threadIdx.x, lane = t & 63, wv = t >> 6;
    if (t == 0) carryS = 0;
    __syncthreads();
    for (int base = 0; base < N_NODES; base += 1024) {
        int idx = base + t;
        int v = (idx < N_NODES) ? offs[idx] : 0;
        if (idx < N_NODES) dinv[idx] = rsqrtf((float)v + 1.0f);
        int s = v;
#pragma unroll
        for (int off = 1; off < 64; off <<= 1) {
            int u = __shfl_up(s, off, 64);
            if (lane >= off) s += u;
        }
        if (lane == 63) wsum[wv] = s;
        __syncthreads();
        int carry = carryS;
        if (wv == 0) {
            int w = (lane < 16) ? wsum[lane] : 0;
#pragma unroll
            for (int off = 1; off < 16; off <<= 1) {
                int u = __shfl_up(w, off, 64);
                if (lane >= off) w += u;
            }
            if (lane < 16) wsum[lane] = w;
        }
        __syncthreads();
        int wbase = (wv == 0) ? 0 : wsum[wv - 1];
        if (idx < N_NODES) offs[idx] = carry + wbase + s - v;
        int total = wsum[15];
        __syncthreads();
        if (t == 0) carryS = carry + total;
        __syncthreads();
    }
    if (t == 0) offs[N_NODES] = carryS;
}

__global__ void k_scatter(const int* __restrict__ srcv, const int* __restrict__ dstv,
                          const float* __restrict__ ea,
                          const int* __restrict__ offs, const float* __restrict__ dinv,
                          int* __restrict__ cursor,
                          int* __restrict__ srcArr, float* __restrict__ dinvArr,
                          uint_t* __restrict__ eaP) {
    int e = blockIdx.x * blockDim.x + threadIdx.x;
    if (e >= N_EDGES) return;
    int d = dstv[e];
    int p = offs[d] + atomicAdd(&cursor[d], 1);
    int s = srcv[e];
    srcArr[p] = s;
    dinvArr[p] = dinv[s];
    const float* er = ea + (size_t)e * EDIM;
    uint_t pk[8];
#pragma unroll
    for (int k2 = 0; k2 < 8; k2++) pk[k2] = pk_f16(er[2 * k2], er[2 * k2 + 1]);
    uint_t* q = eaP + (size_t)p * 8;
    *(uint4*)q = *(uint4*)&pk[0];
    *(uint4*)(q + 4) = *(uint4*)&pk[4];
}

// ---------------- tiled transpose-convert for weights (coalesced) ----------------
__global__ __launch_bounds__(256) void k_cvtW(
    const float* __restrict__ Wf0, const float* __restrict__ Ws0,
    const float* __restrict__ Wf1, const float* __restrict__ Ws1,
    const float* __restrict__ g3W, const float* __restrict__ g4W,
    const float* __restrict__ d1W,
    ushort_t* __restrict__ W2cg0, ushort_t* __restrict__ W2cg1,
    ushort_t* __restrict__ W2g3, ushort_t* __restrict__ W2g4,
    ushort_t* __restrict__ W2d1)
{
    __shared__ ushort_t tle[64][72];
    int b = blockIdx.x, t = threadIdx.x;
    const float* src; int ldw, kin0, cin0, ldk, cout0, kout0; ushort_t* out; float scale;
    if (b < 512) {
        int layer = b >> 8, tt = b & 255;
        int g = tt >> 6, rem = tt & 63;
        int ct = rem >> 3, kt = rem & 7;
        const float* Wf = layer ? Wf1 : Wf0;
        const float* Ws = layer ? Ws1 : Ws0;
        src = (g & 1) ? Ws : Wf;
        ldw = 512; kin0 = ((g & 2) ? 512 : 0) + kt * 64; cin0 = ct * 64;
        out = layer ? W2cg1 : W2cg0; ldk = 512;
        cout0 = g * 512 + ct * 64; kout0 = kt * 64;
        scale = L2E;  // gate weights pre-scaled to exp2 domain
    } else if (b < 544) {
        int tt = b - 512; int ct = tt >> 3, kt = tt & 7;
        src = g3W; ldw = 256; kin0 = kt * 64; cin0 = ct * 64;
        out = W2g3; ldk = 512; cout0 = ct * 64; kout0 = kt * 64; scale = 1.f;
    } else if (b < 560) {
        int tt = b - 544; int ct = tt >> 2, kt = tt & 3;
        src = g4W; ldw = 256; kin0 = kt * 64; cin0 = ct * 64;
        out = W2g4; ldk = 256; cout0 = ct * 64; kout0 = kt * 64; scale = 1.f;
    } else {
        int tt = b - 560; int ct = tt >> 2, kt = tt & 3;
        src = d1W; ldw = 512; kin0 = kt * 64; cin0 = ct * 64;
        out = W2d1; ldk = 256; cout0 = ct * 64; kout0 = kt * 64; scale = 1.f;
    }
    int c = t & 63;
    int k4 = t >> 6;
#pragma unroll
    for (int i = 0; i < 16; i++) {
        int k = k4 * 16 + i;
        tle[k][c] = f2bf(src[(size_t)(kin0 + k) * ldw + cin0 + c] * scale);
    }
    __syncthreads();
    int cl = t >> 2, kq = t & 3;
    ushort_t tmp[16];
#pragma unroll
    for (int j = 0; j < 16; j++) tmp[j] = tle[kq * 16 + j][cl];
    ushort_t* dst = out + (size_t)(cout0 + cl) * ldk + kout0 + kq * 16;
    *(uint4*)dst = *(uint4*)&tmp[0];
    *(uint4*)(dst + 8) = *(uint4*)&tmp[8];
}

// ---------------- mega prep: WEP + goalvec + cvtA ----------------
#define MP_WEP   32
#define MP_GV    40
#define MP_END   20040

__global__ __launch_bounds__(256) void k_megaprep(
    const float* __restrict__ x, const float* __restrict__ goal,
    const float* __restrict__ Wf0, const float* __restrict__ Ws0,
    const float* __restrict__ Wf1, const float* __restrict__ Ws1,
    const float* __restrict__ d1W, const float* __restrict__ d1b,
    ushort_t* __restrict__ A2, uint_t* __restrict__ WEP, float* __restrict__ cgv)
{
    int b = blockIdx.x, t = threadIdx.x;
    if (b < MP_WEP) {
        int layer = b >> 4, blk = b & 15;
        int idx = blk * 256 + t;
        int c = idx >> 3, k2 = idx & 7;
        const float* Wf = (layer ? Wf1 : Wf0) + 1024 * 512;
        const float* Ws = (layer ? Ws1 : Ws0) + 1024 * 512;
        uint_t* WEPf = WEP + layer * 8192;
        uint_t* WEPs = WEPf + 4096;
        WEPf[c * 8 + k2] = pk_f16(Wf[(2 * k2) * 512 + c] * L2E, Wf[(2 * k2 + 1) * 512 + c] * L2E);
        WEPs[c * 8 + k2] = pk_f16(Ws[(2 * k2) * 512 + c] * L2E, Ws[(2 * k2 + 1) * 512 + c] * L2E);
    } else if (b < MP_GV) {
        __shared__ float red[256];
        int bb = b - MP_WEP;
        int c = bb * 64 + (t & 63);
        int slice = t >> 6;
        float acc = 0.f;
        for (int i = 0; i < 128; i++) {
            int k = slice * 128 + i;
            acc += goal[k] * d1W[(size_t)(256 + k) * 512 + c];
        }
        red[t] = acc;
        __syncthreads();
        if (t < 128) red[t] += red[t + 128];
        __syncthreads();
        if (t < 64) cgv[c] = red[t] + red[t + 64] + d1b[c];
    } else {
        int idx = (b - MP_GV) * 256 + t;
        if (idx < N_NODES * 512) {
            int m = idx >> 9, k = idx & 511;
            float v = x[idx];
            ushort_t hi = f2bf(v);
            ushort_t lo = f2bf(v - bf2f(hi));
            size_t rb = (size_t)m * 1024;
            A2[rb + k] = hi;
            A2[rb + 512 + k] = lo;
        }
    }
}

// ---------------- bf16 MFMA GEMM, BM=128, BK=64, B k-wrap (W2t stores KH) ----------------
__global__ __launch_bounds__(256) void k_gemm3(
    const ushort_t* __restrict__ A2, int lda, int KH, int M,
    const ushort_t* __restrict__ W2t,
    float* __restrict__ outF, ushort_t* __restrict__ outQ,
    const float* __restrict__ bias, int mode, int ldc, int gx, int gy)
{
    __shared__ ushort_t As[128 * 64];
    __shared__ ushort_t Bs[128 * 64];
    const int Ktot = 2 * KH;
    int tid = threadIdx.x;
    int lane = tid & 63, w = tid >> 6;
    int wm = w & 1, wn = w >> 1;
    int lrow = lane & 15, quad = lane >> 4;
    int bx, by;
    swz(blockIdx.x, gx, gy, bx, by);
    int row0 = bx * 128, col0 = by * 128;

    f32x4 acc[4][4] = {};

    const ushort_t* ArG[4]; ushort_t* ArL[4];
    const ushort_t* BrG[4]; ushort_t* BrL[4];
#pragma unroll
    for (int p = 0; p < 4; p++) {
        int s = tid + 256 * p;
        int r = s >> 3, k8p = s & 7;
        int k8l = k8p ^ (r & 7);
        int gra = row0 + r; if (gra >= M) gra = M - 1;
        ArG[p] = A2 + (size_t)gra * lda + k8l * 8;
        ArL[p] = As + s * 8;
        BrG[p] = W2t + (size_t)(col0 + r) * KH + k8l * 8;
        BrL[p] = Bs + s * 8;
    }
    const ushort_t* afp[2][4];
    const ushort_t* bfp[2][4];
#pragma unroll
    for (int sl = 0; sl < 2; sl++)
#pragma unroll
        for (int mt = 0; mt < 4; mt++) {
            int r = wm * 64 + mt * 16 + lrow;
            afp[sl][mt] = As + (r * 8 + ((sl * 4 + quad) ^ (r & 7))) * 8;
            int c = wn * 64 + mt * 16 + lrow;
            bfp[sl][mt] = Bs + (c * 8 + ((sl * 4 + quad) ^ (c & 7))) * 8;
        }

    for (int k0 = 0; k0 < Ktot; k0 += 64) {
        int bk0 = k0 & (KH - 1);
        __syncthreads();
#pragma unroll
        for (int p = 0; p < 4; p++) {
            gld16(ArG[p] + k0, ArL[p]);
            gld16(BrG[p] + bk0, BrL[p]);
        }
        __syncthreads();
#pragma unroll
        for (int sl = 0; sl < 2; sl++) {
            bf16x8 af[4], bff[4];
#pragma unroll
            for (int i = 0; i < 4; i++) {
                af[i]  = *(const bf16x8*)afp[sl][i];
                bff[i] = *(const bf16x8*)bfp[sl][i];
            }
#pragma unroll
            for (int mt = 0; mt < 4; mt++)
#pragma unroll
                for (int nt = 0; nt < 4; nt++)
                    acc[mt][nt] = __builtin_amdgcn_mfma_f32_16x16x32_bf16(
                        af[mt], bff[nt], acc[mt][nt], 0, 0, 0);
        }
    }

#pragma unroll
    for (int mt = 0; mt < 4; mt++) {
#pragma unroll
        for (int nt = 0; nt < 4; nt++) {
            int gcol = col0 + wn * 64 + nt * 16 + lrow;
#pragma unroll
            for (int r = 0; r < 4; r++) {
                int grow = row0 + wm * 64 + mt * 16 + quad * 4 + r;
                if (grow >= M) continue;
                float v = acc[mt][nt][r];
                if (mode == 1) {
                    if (gcol < 1024) {
                        outF[(size_t)grow * 1024 + gcol] = v;
                    } else {
                        int c = gcol - 1024;
                        int grp = c >> 9, cc = c & 511;
                        int pos = (cc >> 1) * 4 + grp * 2 + (cc & 1);
                        outQ[(size_t)grow * 1024 + pos] = f2bf(v);
                    }
                } else if (mode == 2) {
                    outF[(size_t)grow * ldc + gcol] = fmaxf(v + bias[gcol], 0.f);
                } else {
                    outQ[(size_t)grow * ldc + gcol] = f2bf(v);
                }
            }
        }
    }
}

// ---------------- bf16 MFMA GEMM, BM=64, BK=64 ----------------
__global__ __launch_bounds__(256) void k_gemm64(
    const ushort_t* __restrict__ A2, int lda, int KH, int M,
    const ushort_t* __restrict__ W2t,
    float* __restrict__ outF, ushort_t* __restrict__ outQ,
    const float* __restrict__ bias, int mode, int ldc, int gx, int gy)
{
    __shared__ ushort_t As[64 * 64];
    __shared__ ushort_t Bs[128 * 64];
    const int Ktot = 2 * KH;
    int tid = threadIdx.x;
    int lane = tid & 63, w = tid >> 6;
    int lrow = lane & 15, quad = lane >> 4;
    int bx, by;
    swz(blockIdx.x, gx, gy, bx, by);
    int row0 = bx * 64, col0 = by * 128;

    f32x4 acc[4][2] = {};

    const ushort_t* ArG[2]; ushort_t* ArL[2];
    const ushort_t* BrG[4]; ushort_t* BrL[4];
#pragma unroll
    for (int p = 0; p < 2; p++) {
        int s = tid + 256 * p;
        int r = s >> 3, k8p = s & 7;
        int k8l = k8p ^ (r & 7);
        int gra = row0 + r; if (gra >= M) gra = M - 1;
        ArG[p] = A2 + (size_t)gra * lda + k8l * 8;
        ArL[p] = As + s * 8;
    }
#pragma unroll
    for (int p = 0; p < 4; p++) {
        int s = tid + 256 * p;
        int r = s >> 3, k8p = s & 7;
        int k8l = k8p ^ (r & 7);
        BrG[p] = W2t + (size_t)(col0 + r) * KH + k8l * 8;
        BrL[p] = Bs + s * 8;
    }
    const ushort_t* afp[2][4];
    const ushort_t* bfp[2][2];
#pragma unroll
    for (int sl = 0; sl < 2; sl++) {
#pragma unroll
        for (int mt = 0; mt < 4; mt++) {
            int r = mt * 16 + lrow;
            afp[sl][mt] = As + (r * 8 + ((sl * 4 + quad) ^ (r & 7))) * 8;
        }
#pragma unroll
        for (int nt = 0; nt < 2; nt++) {
            int c = w * 32 + nt * 16 + lrow;
            bfp[sl][nt] = Bs + (c * 8 + ((sl * 4 + quad) ^ (c & 7))) * 8;
        }
    }

    for (int k0 = 0; k0 < Ktot; k0 += 64) {
        int bk0 = k0 & (KH - 1);
        __syncthreads();
        gld16(ArG[0] + k0, ArL[0]);
        gld16(ArG[1] + k0, ArL[1]);
#pragma unroll
        for (int p = 0; p < 4; p++) gld16(BrG[p] + bk0, BrL[p]);
        __syncthreads();
#pragma unroll
        for (int sl = 0; sl < 2; sl++) {
            bf16x8 af[4], bff[2];
#pragma unroll
            for (int i = 0; i < 4; i++) af[i] = *(const bf16x8*)afp[sl][i];
#pragma unroll
            for (int i = 0; i < 2; i++) bff[i] = *(const bf16x8*)bfp[sl][i];
#pragma unroll
            for (int mt = 0; mt < 4; mt++)
#pragma unroll
                for (int nt = 0; nt < 2; nt++)
                    acc[mt][nt] = __builtin_amdgcn_mfma_f32_16x16x32_bf16(
                        af[mt], bff[nt], acc[mt][nt], 0, 0, 0);
        }
    }

#pragma unroll
    for (int mt = 0; mt < 4; mt++) {
#pragma unroll
        for (int nt = 0; nt < 2; nt++) {
            int gcol = col0 + w * 32 + nt * 16 + lrow;
#pragma unroll
            for (int r = 0; r < 4; r++) {
                int grow = row0 + mt * 16 + quad * 4 + r;
                if (grow >= M) continue;
                float v = acc[mt][nt][r];
                if (mode == 2) outF[(size_t)grow * ldc + gcol] = fmaxf(v + bias[gcol], 0.f);
                else outQ[(size_t)grow * ldc + gcol] = f2bf(v);
            }
        }
    }
}

// ---------------- CGConv aggregation (exp2-domain gates, batch 32) ----------------
__global__ __launch_bounds__(256) void k_cg_aggr(
    const float* __restrict__ xin, const float* __restrict__ P,
    const ushort_t* __restrict__ Qi,
    const uint_t* __restrict__ WEPf, const uint_t* __restrict__ WEPs,
    const float* __restrict__ bfv, const float* __restrict__ bsv,
    const float* __restrict__ gamma, const float* __restrict__ beta,
    const float* __restrict__ mean, const float* __restrict__ var,
    const int* __restrict__ offs, const int* __restrict__ srcArr,
    const uint_t* __restrict__ eaP,
    float* __restrict__ xout, ushort_t* __restrict__ A2out)
{
    int i = blockIdx.x;
    int t = threadIdx.x;
    int c0 = 2 * t;
    uint_t wfp[2][8], wsp[2][8];
    {
        const uint_t* pf8 = WEPf + c0 * 8;
        const uint_t* ps8 = WEPs + c0 * 8;
        *(uint4*)&wfp[0][0] = *(const uint4*)(pf8 + 0);
        *(uint4*)&wfp[0][4] = *(const uint4*)(pf8 + 4);
        *(uint4*)&wfp[1][0] = *(const uint4*)(pf8 + 8);
        *(uint4*)&wfp[1][4] = *(const uint4*)(pf8 + 12);
        *(uint4*)&wsp[0][0] = *(const uint4*)(ps8 + 0);
        *(uint4*)&wsp[0][4] = *(const uint4*)(ps8 + 4);
        *(uint4*)&wsp[1][0] = *(const uint4*)(ps8 + 8);
        *(uint4*)&wsp[1][4] = *(const uint4*)(ps8 + 12);
    }
    float2 pf = *(const float2*)&P[(size_t)i * 1024 + c0];
    float2 ps = *(const float2*)&P[(size_t)i * 1024 + 512 + c0];
    float2 bf2 = *(const float2*)&bfv[c0];
    float2 bs2 = *(const float2*)&bsv[c0];
    pf.x = fmaf(bf2.x, L2E, pf.x); pf.y = fmaf(bf2.y, L2E, pf.y);
    ps.x = fmaf(bs2.x, L2E, ps.x); ps.y = fmaf(bs2.y, L2E, ps.y);
    float acc0 = 0.f, acc1 = 0.f;
    int e0 = offs[i], e1 = offs[i + 1];
    __shared__ uint_t sEaP[32][8];
    __shared__ int sSrc[34];
    const ushort_t* Qbase = Qi + 4 * t;
    for (int base = e0; base < e1; base += 32) {
        int g = min(32, e1 - base);
        __syncthreads();
        if (t < 34) {
            int s = 0;
            if (t < g) s = srcArr[base + t];
            sSrc[t] = s;
        }
        {
            int j = t >> 3, k2 = t & 7;
            if (j < g) sEaP[j][k2] = eaP[(size_t)(base + j) * 8 + k2];
        }
        __syncthreads();
        uint2 q0 = *(const uint2*)(Qbase + ((size_t)sSrc[0] << 10));
        uint2 q1 = *(const uint2*)(Qbase + ((size_t)sSrc[1] << 10));
        for (int j = 0; j < g; j++) {
            uint2 qn = *(const uint2*)(Qbase + ((size_t)sSrc[j + 2] << 10));
            uint4 eA = *(const uint4*)&sEaP[j][0];
            uint4 eB = *(const uint4*)&sEaP[j][4];
            float gf0 = pf.x + bflo(q0.x), gf1 = pf.y + bfhi(q0.x);
            float gs0 = ps.x + bflo(q0.y), gs1 = ps.y + bfhi(q0.y);
            uint_t ek[8] = {eA.x, eA.y, eA.z, eA.w, eB.x, eB.y, eB.z, eB.w};
#pragma unroll
            for (int k = 0; k < 8; k++) {
                half2_t e2 = u2h(ek[k]);
                gf0 = __builtin_amdgcn_fdot2(e2, u2h(wfp[0][k]), gf0, false);
                gf1 = __builtin_amdgcn_fdot2(e2, u2h(wfp[1][k]), gf1, false);
                gs0 = __builtin_amdgcn_fdot2(e2, u2h(wsp[0][k]), gs0, false);
                gs1 = __builtin_amdgcn_fdot2(e2, u2h(wsp[1][k]), gs1, false);
            }
            // exp2-domain: g* are true-gate * log2(e); raw v_exp/v_log ops
            float sg0 = __builtin_amdgcn_rcpf(1.f + fexp2(-gf0));
            float sg1 = __builtin_amdgcn_rcpf(1.f + fexp2(-gf1));
            float sp0 = fmaxf(gs0, 0.f) + flog2(1.f + fexp2(-fabsf(gs0)));
            float sp1 = fmaxf(gs1, 0.f) + flog2(1.f + fexp2(-fabsf(gs1)));
            acc0 = fmaf(sg0, sp0, acc0);
            acc1 = fmaf(sg1, sp1, acc1);
            q0 = q1; q1 = qn;
        }
    }
    acc0 *= LN2;  // softplus ln2 factor folded out of the edge sum
    acc1 *= LN2;
    size_t ib = (size_t)i * DIM;
    float2 mn = *(const float2*)&mean[c0];
    float2 vr = *(const float2*)&var[c0];
    float2 gm = *(const float2*)&gamma[c0];
    float2 bt = *(const float2*)&beta[c0];
    float2 xi = *(const float2*)&xin[ib + c0];
    float bn0 = (acc0 - mn.x) * rsqrtf(vr.x + BN_EPS) * gm.x + bt.x;
    float bn1 = (acc1 - mn.y) * rsqrtf(vr.y + BN_EPS) * gm.y + bt.y;
    float o0 = fmaxf(xi.x + bn0, 0.f);
    float o1 = fmaxf(xi.y + bn1, 0.f);
    *(float2*)&xout[ib + c0] = make_float2(o0, o1);
    ushort_t h0 = f2bf(o0), h1 = f2bf(o1);
    ushort_t l0 = f2bf(o0 - bf2f(h0)), l1 = f2bf(o1 - bf2f(h1));
    *(uint_t*)(A2out + (size_t)i * 1024 + c0)       = (uint_t)h0 | ((uint_t)h1 << 16);
    *(uint_t*)(A2out + (size_t)i * 1024 + 512 + c0) = (uint_t)l0 | ((uint_t)l1 << 16);
}

// ---------------- GCN aggregation (batch 32) ----------------
__global__ __launch_bounds__(128) void k_gcn_aggr(
    const ushort_t* __restrict__ h, const float* __restrict__ dinv,
    const float* __restrict__ bias,
    const int* __restrict__ offs, const int* __restrict__ srcArr,
    const float* __restrict__ dinvArr, ushort_t* __restrict__ A2out)
{
    int i = blockIdx.x;
    int t = threadIdx.x;
    int c0 = 2 * t;
    float acc0 = 0.f, acc1 = 0.f;
    int e0 = offs[i], e1 = offs[i + 1];
    __shared__ int sS[36];
    __shared__ float sD[36];
    for (int base = e0; base < e1; base += 32) {
        int g = min(32, e1 - base);
        __syncthreads();
        if (t < 36) {
            bool ok = (t < g);
            sS[t] = ok ? srcArr[base + t] : 0;
            sD[t] = ok ? dinvArr[base + t] : 0.f;
        }
        __syncthreads();
        uint_t q0 = *(const uint_t*)(h + (size_t)sS[0] * HDIM + c0);
        uint_t q1 = *(const uint_t*)(h + (size_t)sS[1] * HDIM + c0);
        uint_t q2 = *(const uint_t*)(h + (size_t)sS[2] * HDIM + c0);
        uint_t q3 = *(const uint_t*)(h + (size_t)sS[3] * HDIM + c0);
        for (int j = 0; j < g; j++) {
            uint_t qn = *(const uint_t*)(h + (size_t)sS[j + 4] * HDIM + c0);
            acc0 += sD[j] * bflo(q0);
            acc1 += sD[j] * bfhi(q0);
            q0 = q1; q1 = q2; q2 = q3; q3 = qn;
        }
    }
    float di = dinv[i];
    uint_t qi = *(const uint_t*)(h + (size_t)i * HDIM + c0);
    float2 b2 = *(const float2*)&bias[c0];
    float o0 = fmaxf(di * acc0 + di * di * bflo(qi) + b2.x, 0.f);
    float o1 = fmaxf(di * acc1 + di * di * bfhi(qi) + b2.y, 0.f);
    ushort_t h0 = f2bf(o0), h1 = f2bf(o1);
    ushort_t l0 = f2bf(o0 - bf2f(h0)), l1 = f2bf(o1 - bf2f(h1));
    *(uint_t*)(A2out + (size_t)i * 512 + c0)       = (uint_t)h0 | ((uint_t)h1 << 16);
    *(uint_t*)(A2out + (size_t)i * 512 + 256 + c0) = (uint_t)l0 | ((uint_t)l1 << 16);
}

// ---------------- final dot ----------------
__global__ __launch_bounds__(256) void k_final(const float* __restrict__ hd,
                                               const float* __restrict__ w2,
                                               const float* __restrict__ b2,
                                               float* __restrict__ out) {
    int wave = threadIdx.x >> 6, lane = threadIdx.x & 63;
    int i = blockIdx.x * 4 + wave;
    if (i >= N_NODES) return;
    const float* r = hd + (size_t)i * DIM;
    float acc = 0.f;
#pragma unroll
    for (int q = 0; q < 8; q++) acc += r[lane + 64 * q] * w2[lane + 64 * q];
#pragma unroll
    for (int off = 32; off > 0; off >>= 1) acc += __shfl_down(acc, off, 64);
    if (lane == 0) out[i] = acc + b2[0];
}

// ---------------- launch ----------------
extern "C" void kernel_launch(void* const* d_in, const int* in_sizes, int n_in,
                              void* d_out, int out_size, void* d_ws, size_t ws_size,
                              hipStream_t stream) {
    (void)in_sizes; (void)n_in; (void)out_size; (void)ws_size;
    const float* x      = (const float*)d_in[0];
    const float* ea     = (const float*)d_in[1];
    const float* goal   = (const float*)d_in[2];
    const float* cgWf[2] = {(const float*)d_in[3],  (const float*)d_in[11]};
    const float* cgbf[2] = {(const float*)d_in[4],  (const float*)d_in[12]};
    const float* cgWs[2] = {(const float*)d_in[5],  (const float*)d_in[13]};
    const float* cgbs[2] = {(const float*)d_in[6],  (const float*)d_in[14]};
    const float* cggm[2] = {(const float*)d_in[7],  (const float*)d_in[15]};
    const float* cgbt[2] = {(const float*)d_in[8],  (const float*)d_in[16]};
    const float* cgmn[2] = {(const float*)d_in[9],  (const float*)d_in[17]};
    const float* cgvr[2] = {(const float*)d_in[10], (const float*)d_in[18]};
    const float* gcn3_W = (const float*)d_in[19];
    const float* gcn3_b = (const float*)d_in[20];
    const float* gcn4_W = (const float*)d_in[21];
    const float* gcn4_b = (const float*)d_in[22];
    const float* d1_W   = (const float*)d_in[23];
    const float* d1_b   = (const float*)d_in[24];
    const float* d2_W   = (const float*)d_in[25];
    const float* d2_b   = (const float*)d_in[26];
    const int*   eidx   = (const int*)d_in[27];
    const int*   srcv   = eidx;
    const int*   dstv   = eidx + N_EDGES;
    float* outp = (float*)d_out;

    // ---- workspace layout (~113 MB) ----
    char* w = (char*)d_ws;
    float*    Pbuf  = (float*)w;                      w += (size_t)N_NODES * 1024 * 4;
    ushort_t* Qbuf  = (ushort_t*)w;                   w += (size_t)N_NODES * 1024 * 2;
    float*    xB    = (float*)w;                      w += (size_t)N_NODES * 512 * 4;
    ushort_t* A2    = (ushort_t*)w;                   w += (size_t)N_NODES * 1024 * 2;
    ushort_t* W2cg0 = (ushort_t*)w;                   w += (size_t)2048 * 512 * 2;
    ushort_t* W2cg1 = (ushort_t*)w;                   w += (size_t)2048 * 512 * 2;
    ushort_t* W2g3  = (ushort_t*)w;                   w += (size_t)256 * 512 * 2;
    ushort_t* W2g4  = (ushort_t*)w;                   w += (size_t)256 * 256 * 2;
    ushort_t* W2d1  = (ushort_t*)w;                   w += (size_t)512 * 256 * 2;
    uint_t*   eaP   = (uint_t*)w;                     w += (size_t)N_EDGES * 8 * 4;
    uint_t*   WEP   = (uint_t*)w;                     w += 16384 * 4;
    float*    cgv   = (float*)w;                      w += 512 * 4;
    int*      srcArr  = (int*)w;                      w += N_EDGES * 4;
    float*    dinvArr = (float*)w;                    w += N_EDGES * 4;
    int*      offs    = (int*)w;                      w += (N_NODES + 1) * 4;
    int*      cursor  = (int*)w;                      w += N_NODES * 4;
    float*    dinv    = (float*)w;                    w += N_NODES * 4;
    uint_t* WEPf[2] = {WEP, WEP + 8192};
    uint_t* WEPs[2] = {WEP + 4096, WEP + 12288};
    ushort_t* h3 = (ushort_t*)Pbuf;
    ushort_t* h4 = h3 + (size_t)N_NODES * HDIM;
    float*    hd = (float*)Qbuf;

    // ---- prep ----
    k_cvtW<<<592, 256, 0, stream>>>(cgWf[0], cgWs[0], cgWf[1], cgWs[1],
                                    gcn3_W, gcn4_W, d1_W,
                                    W2cg0, W2cg1, W2g3, W2g4, W2d1);
    k_megaprep<<<MP_END, 256, 0, stream>>>(x, goal,
        cgWf[0], cgWs[0], cgWf[1], cgWs[1], d1_W, d1_b, A2, WEP, cgv);

    // ---- CSR build ----
    hipMemsetAsync(offs, 0, (N_NODES + 1) * sizeof(int), stream);
    hipMemsetAsync(cursor, 0, N_NODES * sizeof(int), stream);
    k_hist<<<(N_EDGES + 255) / 256, 256, 0, stream>>>(dstv, offs);
    k_scan<<<1, 1024, 0, stream>>>(offs, dinv);
    k_scatter<<<(N_EDGES + 255) / 256, 256, 0, stream>>>(srcv, dstv, ea, offs, dinv,
                                                         cursor, srcArr, dinvArr, eaP);

    // ---- CG layer 1 ----
    k_gemm3<<<79 * 16, 256, 0, stream>>>(A2, 1024, 512, N_NODES, W2cg0,
                                         Pbuf, Qbuf, nullptr, 1, 0, 79, 16);
    k_cg_aggr<<<N_NODES, 256, 0, stream>>>(x, Pbuf, Qbuf, WEPf[0], WEPs[0],
                                           cgbf[0], cgbs[0],
                                           cggm[0], cgbt[0], cgmn[0], cgvr[0],
                                           offs, srcArr, eaP, xB, A2);
    // ---- CG layer 2 ----
    k_gemm3<<<79 * 16, 256, 0, stream>>>(A2, 1024, 512, N_NODES, W2cg1,
                                         Pbuf, Qbuf, nullptr, 1, 0, 79, 16);
    k_cg_aggr<<<N_NODES, 256, 0, stream>>>(xB, Pbuf, Qbuf, WEPf[1], WEPs[1],
                                           cgbf[1], cgbs[1],
                                           cggm[1], cgbt[1], cgmn[1], cgvr[1],
                                           offs, srcArr, eaP, xB, A2);

    // ---- GCN 3: 512 -> 256 ----
    k_gemm64<<<157 * 2, 256, 0, stream>>>(A2, 1024, 512, N_NODES, W2g3,
                                          nullptr, h3, nullptr, 3, HDIM, 157, 2);
    k_gcn_aggr<<<N_NODES, 128, 0, stream>>>(h3, dinv, gcn3_b, offs, srcArr, dinvArr, A2);

    // ---- GCN 4: 256 -> 256 ----
    k_gemm64<<<157 * 2, 256, 0, stream>>>(A2, 512, 256, N_NODES, W2g4,
                                          nullptr, h4, nullptr, 3, HDIM, 157, 2);
    k_gcn_aggr<<<N_NODES, 128, 0, stream>>>(h4, dinv, gcn4_b, offs, srcArr, dinvArr, A2);

    // ---- dense head ----
    k_gemm64<<<157 * 4, 256, 0, stream>>>(A2, 512, 256, N_NODES, W2d1,
                                          hd, nullptr, cgv, 2, DIM, 157, 4);
    k_final<<<(N_NODES + 3) / 4, 256, 0, stream>>>(hd, d2_W, d2_b, outp);
}

// Round 10
// 556.437 us; speedup vs baseline: 1.2186x; 1.1314x over previous
//
#include <hip/hip_runtime.h>
#include <math.h>

#define N_NODES 10000
#define N_EDGES 160000
#define DIM 512
#define HDIM 256
#define EDIM 16
#define BN_EPS 1e-5f
#define L2E 1.4426950408889634f
#define LN2 0.6931471805599453f

typedef unsigned short ushort_t;
typedef unsigned int uint_t;
typedef __attribute__((ext_vector_type(8))) short bf16x8;
typedef __attribute__((ext_vector_type(4))) float f32x4;
typedef __attribute__((ext_vector_type(2))) _Float16 half2_t;

// ---------------- helpers ----------------
__device__ __forceinline__ ushort_t f2bf(float x) {
    uint_t u = __float_as_uint(x);
    uint_t r = (u + 0x7FFF + ((u >> 16) & 1)) >> 16;  // RNE
    return (ushort_t)r;
}
__device__ __forceinline__ float bf2f(ushort_t h) {
    return __uint_as_float(((uint_t)h) << 16);
}
__device__ __forceinline__ float bflo(uint_t u) {
    return __uint_as_float(u << 16);
}
__device__ __forceinline__ float bfhi(uint_t u) {
    return __uint_as_float(u & 0xffff0000u);
}
__device__ __forceinline__ void gld16(const void* g, void* l) {
    __builtin_amdgcn_global_load_lds(
        (const __attribute__((address_space(1))) unsigned int*)g,
        (__attribute__((address_space(3))) unsigned int*)l, 16, 0, 0);
}
__device__ __forceinline__ half2_t u2h(uint_t u) {
    return __builtin_bit_cast(half2_t, u);
}
__device__ __forceinline__ uint_t pk_f16(float a, float b) {
    return __builtin_bit_cast(uint_t, __builtin_amdgcn_cvt_pkrtz(a, b));
}
// raw HW transcendentals: v_exp_f32 (2^x), v_log_f32 (log2 x)
__device__ __forceinline__ float fexp2(float x) {
#if __has_builtin(__builtin_amdgcn_exp2f)
    return __builtin_amdgcn_exp2f(x);
#else
    return __expf(x * LN2);
#endif
}
__device__ __forceinline__ float flog2(float x) {
#if __has_builtin(__builtin_amdgcn_logf)
    return __builtin_amdgcn_logf(x);
#else
    return __logf(x) * L2E;
#endif
}
__device__ __forceinline__ void swz(int lid, int gx, int gy, int& bx, int& by) {
    int per = gy * 8;
    int grp = lid / per;
    int rem = lid - grp * per;
    int gsz = min(8, gx - grp * 8);
    by = rem / gsz;
    bx = grp * 8 + (rem - by * gsz);
}

// ---------------- CSR build ----------------
__global__ void k_hist(const int* __restrict__ dst, int* __restrict__ cnt) {
    int e = blockIdx.x * blockDim.x + threadIdx.x;
    if (e < N_EDGES) atomicAdd(&cnt[dst[e]], 1);
}

__global__ __launch_bounds__(1024) void k_scan(int* __restrict__ offs, float* __restrict__ dinv) {
    __shared__ int wsum[16];
    __shared__ int carryS;
    int t = threadIdx.x, lane = t & 63, wv = t >> 6;
    if (t == 0) carryS = 0;
    __syncthreads();
    for (int base = 0; base < N_NODES; base += 1024) {
        int idx = base + t;
        int v = (idx < N_NODES) ? offs[idx] : 0;
        if (idx < N_NODES) dinv[idx] = rsqrtf((float)v + 1.0f);
        int s = v;
#pragma unroll
        for (int off = 1; off < 64; off <<= 1) {
            int u = __shfl_up(s, off, 64);
            if (lane >= off) s += u;
        }
        if (lane == 63) wsum[wv] = s;
        __syncthreads();
        int carry = carryS;
        if (wv == 0) {
            int w = (lane < 16) ? wsum[lane] : 0;
#pragma unroll
            for (int off = 1; off < 16; off <<= 1) {
                int u = __shfl_up(w, off, 64);
                if (lane >= off) w += u;
            }
            if (lane < 16) wsum[lane] = w;
        }
        __syncthreads();
        int wbase = (wv == 0) ? 0 : wsum[wv - 1];
        if (idx < N_NODES) offs[idx] = carry + wbase + s - v;
        int total = wsum[15];
        __syncthreads();
        if (t == 0) carryS = carry + total;
        __syncthreads();
    }
    if (t == 0) offs[N_NODES] = carryS;
}

__global__ void k_scatter(const int* __restrict__ srcv, const int* __restrict__ dstv,
                          const float* __restrict__ ea,
                          const int* __restrict__ offs, const float* __restrict__ dinv,
                          int* __restrict__ cursor,
                          int* __restrict__ srcArr, float* __restrict__ dinvArr,
                          uint_t* __restrict__ eaP) {
    int e = blockIdx.x * blockDim.x + threadIdx.x;
    if (e >= N_EDGES) return;
    int d = dstv[e];
    int p = offs[d] + atomicAdd(&cursor[d], 1);
    int s = srcv[e];
    srcArr[p] = s;
    dinvArr[p] = dinv[s];
    const float* er = ea + (size_t)e * EDIM;
    uint_t pk[8];
#pragma unroll
    for (int k2 = 0; k2 < 8; k2++) pk[k2] = pk_f16(er[2 * k2], er[2 * k2 + 1]);
    uint_t* q = eaP + (size_t)p * 8;
    *(uint4*)q = *(uint4*)&pk[0];
    *(uint4*)(q + 4) = *(uint4*)&pk[4];
}

// ---------------- tiled transpose-convert for weights (coalesced) ----------------
__global__ __launch_bounds__(256) void k_cvtW(
    const float* __restrict__ Wf0, const float* __restrict__ Ws0,
    const float* __restrict__ Wf1, const float* __restrict__ Ws1,
    const float* __restrict__ g3W, const float* __restrict__ g4W,
    const float* __restrict__ d1W,
    ushort_t* __restrict__ W2cg0, ushort_t* __restrict__ W2cg1,
    ushort_t* __restrict__ W2g3, ushort_t* __restrict__ W2g4,
    ushort_t* __restrict__ W2d1)
{
    __shared__ ushort_t tle[64][72];
    int b = blockIdx.x, t = threadIdx.x;
    const float* src; int ldw, kin0, cin0, ldk, cout0, kout0; ushort_t* out; float scale;
    if (b < 512) {
        int layer = b >> 8, tt = b & 255;
        int g = tt >> 6, rem = tt & 63;
        int ct = rem >> 3, kt = rem & 7;
        const float* Wf = layer ? Wf1 : Wf0;
        const float* Ws = layer ? Ws1 : Ws0;
        src = (g & 1) ? Ws : Wf;
        ldw = 512; kin0 = ((g & 2) ? 512 : 0) + kt * 64; cin0 = ct * 64;
        out = layer ? W2cg1 : W2cg0; ldk = 512;
        cout0 = g * 512 + ct * 64; kout0 = kt * 64;
        scale = L2E;  // gate weights pre-scaled to exp2 domain
    } else if (b < 544) {
        int tt = b - 512; int ct = tt >> 3, kt = tt & 7;
        src = g3W; ldw = 256; kin0 = kt * 64; cin0 = ct * 64;
        out = W2g3; ldk = 512; cout0 = ct * 64; kout0 = kt * 64; scale = 1.f;
    } else if (b < 560) {
        int tt = b - 544; int ct = tt >> 2, kt = tt & 3;
        src = g4W; ldw = 256; kin0 = kt * 64; cin0 = ct * 64;
        out = W2g4; ldk = 256; cout0 = ct * 64; kout0 = kt * 64; scale = 1.f;
    } else {
        int tt = b - 560; int ct = tt >> 2, kt = tt & 3;
        src = d1W; ldw = 512; kin0 = kt * 64; cin0 = ct * 64;
        out = W2d1; ldk = 256; cout0 = ct * 64; kout0 = kt * 64; scale = 1.f;
    }
    int c = t & 63;
    int k4 = t >> 6;
#pragma unroll
    for (int i = 0; i < 16; i++) {
        int k = k4 * 16 + i;
        tle[k][c] = f2bf(src[(size_t)(kin0 + k) * ldw + cin0 + c] * scale);
    }
    __syncthreads();
    int cl = t >> 2, kq = t & 3;
    ushort_t tmp[16];
#pragma unroll
    for (int j = 0; j < 16; j++) tmp[j] = tle[kq * 16 + j][cl];
    ushort_t* dst = out + (size_t)(cout0 + cl) * ldk + kout0 + kq * 16;
    *(uint4*)dst = *(uint4*)&tmp[0];
    *(uint4*)(dst + 8) = *(uint4*)&tmp[8];
}

// ---------------- mega prep: WEP + goalvec + cvtA (single bf16) ----------------
#define MP_WEP   32
#define MP_GV    40
#define MP_END   20040

__global__ __launch_bounds__(256) void k_megaprep(
    const float* __restrict__ x, const float* __restrict__ goal,
    const float* __restrict__ Wf0, const float* __restrict__ Ws0,
    const float* __restrict__ Wf1, const float* __restrict__ Ws1,
    const float* __restrict__ d1W, const float* __restrict__ d1b,
    ushort_t* __restrict__ A2, uint_t* __restrict__ WEP, float* __restrict__ cgv)
{
    int b = blockIdx.x, t = threadIdx.x;
    if (b < MP_WEP) {
        int layer = b >> 4, blk = b & 15;
        int idx = blk * 256 + t;
        int c = idx >> 3, k2 = idx & 7;
        const float* Wf = (layer ? Wf1 : Wf0) + 1024 * 512;
        const float* Ws = (layer ? Ws1 : Ws0) + 1024 * 512;
        uint_t* WEPf = WEP + layer * 8192;
        uint_t* WEPs = WEPf + 4096;
        WEPf[c * 8 + k2] = pk_f16(Wf[(2 * k2) * 512 + c] * L2E, Wf[(2 * k2 + 1) * 512 + c] * L2E);
        WEPs[c * 8 + k2] = pk_f16(Ws[(2 * k2) * 512 + c] * L2E, Ws[(2 * k2 + 1) * 512 + c] * L2E);
    } else if (b < MP_GV) {
        __shared__ float red[256];
        int bb = b - MP_WEP;
        int c = bb * 64 + (t & 63);
        int slice = t >> 6;
        float acc = 0.f;
        for (int i = 0; i < 128; i++) {
            int k = slice * 128 + i;
            acc += goal[k] * d1W[(size_t)(256 + k) * 512 + c];
        }
        red[t] = acc;
        __syncthreads();
        if (t < 128) red[t] += red[t + 128];
        __syncthreads();
        if (t < 64) cgv[c] = red[t] + red[t + 64] + d1b[c];
    } else {
        int idx = (b - MP_GV) * 256 + t;
        if (idx < N_NODES * 512) A2[idx] = f2bf(x[idx]);
    }
}

// ---------------- bf16 MFMA GEMM, BM=128, BK=64 ----------------
// mode 1: CG (cols<1024 -> outF f32 ld 1024; cols>=1024 -> outQ interleaved bf16)
__global__ __launch_bounds__(256) void k_gemm3(
    const ushort_t* __restrict__ A2, int K, int M,
    const ushort_t* __restrict__ W2t,
    float* __restrict__ outF, ushort_t* __restrict__ outQ,
    const float* __restrict__ bias, int mode, int ldc, int gx, int gy)
{
    __shared__ ushort_t As[128 * 64];
    __shared__ ushort_t Bs[128 * 64];
    int tid = threadIdx.x;
    int lane = tid & 63, w = tid >> 6;
    int wm = w & 1, wn = w >> 1;
    int lrow = lane & 15, quad = lane >> 4;
    int bx, by;
    swz(blockIdx.x, gx, gy, bx, by);
    int row0 = bx * 128, col0 = by * 128;

    f32x4 acc[4][4] = {};

    const ushort_t* ArG[4]; ushort_t* ArL[4];
    const ushort_t* BrG[4]; ushort_t* BrL[4];
#pragma unroll
    for (int p = 0; p < 4; p++) {
        int s = tid + 256 * p;
        int r = s >> 3, k8p = s & 7;
        int k8l = k8p ^ (r & 7);
        int gra = row0 + r; if (gra >= M) gra = M - 1;
        ArG[p] = A2 + (size_t)gra * K + k8l * 8;
        ArL[p] = As + s * 8;
        BrG[p] = W2t + (size_t)(col0 + r) * K + k8l * 8;
        BrL[p] = Bs + s * 8;
    }
    const ushort_t* afp[2][4];
    const ushort_t* bfp[2][4];
#pragma unroll
    for (int sl = 0; sl < 2; sl++)
#pragma unroll
        for (int mt = 0; mt < 4; mt++) {
            int r = wm * 64 + mt * 16 + lrow;
            afp[sl][mt] = As + (r * 8 + ((sl * 4 + quad) ^ (r & 7))) * 8;
            int c = wn * 64 + mt * 16 + lrow;
            bfp[sl][mt] = Bs + (c * 8 + ((sl * 4 + quad) ^ (c & 7))) * 8;
        }

    for (int k0 = 0; k0 < K; k0 += 64) {
        __syncthreads();
#pragma unroll
        for (int p = 0; p < 4; p++) {
            gld16(ArG[p] + k0, ArL[p]);
            gld16(BrG[p] + k0, BrL[p]);
        }
        __syncthreads();
#pragma unroll
        for (int sl = 0; sl < 2; sl++) {
            bf16x8 af[4], bff[4];
#pragma unroll
            for (int i = 0; i < 4; i++) {
                af[i]  = *(const bf16x8*)afp[sl][i];
                bff[i] = *(const bf16x8*)bfp[sl][i];
            }
#pragma unroll
            for (int mt = 0; mt < 4; mt++)
#pragma unroll
                for (int nt = 0; nt < 4; nt++)
                    acc[mt][nt] = __builtin_amdgcn_mfma_f32_16x16x32_bf16(
                        af[mt], bff[nt], acc[mt][nt], 0, 0, 0);
        }
    }

#pragma unroll
    for (int mt = 0; mt < 4; mt++) {
#pragma unroll
        for (int nt = 0; nt < 4; nt++) {
            int gcol = col0 + wn * 64 + nt * 16 + lrow;
#pragma unroll
            for (int r = 0; r < 4; r++) {
                int grow = row0 + wm * 64 + mt * 16 + quad * 4 + r;
                if (grow >= M) continue;
                float v = acc[mt][nt][r];
                if (mode == 1) {
                    if (gcol < 1024) {
                        outF[(size_t)grow * 1024 + gcol] = v;
                    } else {
                        int c = gcol - 1024;
                        int grp = c >> 9, cc = c & 511;
                        int pos = (cc >> 1) * 4 + grp * 2 + (cc & 1);
                        outQ[(size_t)grow * 1024 + pos] = f2bf(v);
                    }
                } else if (mode == 2) {
                    outF[(size_t)grow * ldc + gcol] = fmaxf(v + bias[gcol], 0.f);
                } else {
                    outQ[(size_t)grow * ldc + gcol] = f2bf(v);
                }
            }
        }
    }
}

// ---------------- bf16 MFMA GEMM, BM=64, BK=64 ----------------
__global__ __launch_bounds__(256) void k_gemm64(
    const ushort_t* __restrict__ A2, int K, int M,
    const ushort_t* __restrict__ W2t,
    float* __restrict__ outF, ushort_t* __restrict__ outQ,
    const float* __restrict__ bias, int mode, int ldc, int gx, int gy)
{
    __shared__ ushort_t As[64 * 64];
    __shared__ ushort_t Bs[128 * 64];
    int tid = threadIdx.x;
    int lane = tid & 63, w = tid >> 6;
    int lrow = lane & 15, quad = lane >> 4;
    int bx, by;
    swz(blockIdx.x, gx, gy, bx, by);
    int row0 = bx * 64, col0 = by * 128;

    f32x4 acc[4][2] = {};

    const ushort_t* ArG[2]; ushort_t* ArL[2];
    const ushort_t* BrG[4]; ushort_t* BrL[4];
#pragma unroll
    for (int p = 0; p < 2; p++) {
        int s = tid + 256 * p;
        int r = s >> 3, k8p = s & 7;
        int k8l = k8p ^ (r & 7);
        int gra = row0 + r; if (gra >= M) gra = M - 1;
        ArG[p] = A2 + (size_t)gra * K + k8l * 8;
        ArL[p] = As + s * 8;
    }
#pragma unroll
    for (int p = 0; p < 4; p++) {
        int s = tid + 256 * p;
        int r = s >> 3, k8p = s & 7;
        int k8l = k8p ^ (r & 7);
        BrG[p] = W2t + (size_t)(col0 + r) * K + k8l * 8;
        BrL[p] = Bs + s * 8;
    }
    const ushort_t* afp[2][4];
    const ushort_t* bfp[2][2];
#pragma unroll
    for (int sl = 0; sl < 2; sl++) {
#pragma unroll
        for (int mt = 0; mt < 4; mt++) {
            int r = mt * 16 + lrow;
            afp[sl][mt] = As + (r * 8 + ((sl * 4 + quad) ^ (r & 7))) * 8;
        }
#pragma unroll
        for (int nt = 0; nt < 2; nt++) {
            int c = w * 32 + nt * 16 + lrow;
            bfp[sl][nt] = Bs + (c * 8 + ((sl * 4 + quad) ^ (c & 7))) * 8;
        }
    }

    for (int k0 = 0; k0 < K; k0 += 64) {
        __syncthreads();
        gld16(ArG[0] + k0, ArL[0]);
        gld16(ArG[1] + k0, ArL[1]);
#pragma unroll
        for (int p = 0; p < 4; p++) gld16(BrG[p] + k0, BrL[p]);
        __syncthreads();
#pragma unroll
        for (int sl = 0; sl < 2; sl++) {
            bf16x8 af[4], bff[2];
#pragma unroll
            for (int i = 0; i < 4; i++) af[i] = *(const bf16x8*)afp[sl][i];
#pragma unroll
            for (int i = 0; i < 2; i++) bff[i] = *(const bf16x8*)bfp[sl][i];
#pragma unroll
            for (int mt = 0; mt < 4; mt++)
#pragma unroll
                for (int nt = 0; nt < 2; nt++)
                    acc[mt][nt] = __builtin_amdgcn_mfma_f32_16x16x32_bf16(
                        af[mt], bff[nt], acc[mt][nt], 0, 0, 0);
        }
    }

#pragma unroll
    for (int mt = 0; mt < 4; mt++) {
#pragma unroll
        for (int nt = 0; nt < 2; nt++) {
            int gcol = col0 + w * 32 + nt * 16 + lrow;
#pragma unroll
            for (int r = 0; r < 4; r++) {
                int grow = row0 + mt * 16 + quad * 4 + r;
                if (grow >= M) continue;
                float v = acc[mt][nt][r];
                if (mode == 2) outF[(size_t)grow * ldc + gcol] = fmaxf(v + bias[gcol], 0.f);
                else outQ[(size_t)grow * ldc + gcol] = f2bf(v);
            }
        }
    }
}

// ---------------- CGConv aggregation (exp2-domain gates, batch 32) ----------------
// writes A2out (bf16, lda 512) always; xout (fp32) only if non-null
__global__ __launch_bounds__(256) void k_cg_aggr(
    const float* __restrict__ xin, const float* __restrict__ P,
    const ushort_t* __restrict__ Qi,
    const uint_t* __restrict__ WEPf, const uint_t* __restrict__ WEPs,
    const float* __restrict__ bfv, const float* __restrict__ bsv,
    const float* __restrict__ gamma, const float* __restrict__ beta,
    const float* __restrict__ mean, const float* __restrict__ var,
    const int* __restrict__ offs, const int* __restrict__ srcArr,
    const uint_t* __restrict__ eaP,
    float* __restrict__ xout, ushort_t* __restrict__ A2out)
{
    int i = blockIdx.x;
    int t = threadIdx.x;
    int c0 = 2 * t;
    uint_t wfp[2][8], wsp[2][8];
    {
        const uint_t* pf8 = WEPf + c0 * 8;
        const uint_t* ps8 = WEPs + c0 * 8;
        *(uint4*)&wfp[0][0] = *(const uint4*)(pf8 + 0);
        *(uint4*)&wfp[0][4] = *(const uint4*)(pf8 + 4);
        *(uint4*)&wfp[1][0] = *(const uint4*)(pf8 + 8);
        *(uint4*)&wfp[1][4] = *(const uint4*)(pf8 + 12);
        *(uint4*)&wsp[0][0] = *(const uint4*)(ps8 + 0);
        *(uint4*)&wsp[0][4] = *(const uint4*)(ps8 + 4);
        *(uint4*)&wsp[1][0] = *(const uint4*)(ps8 + 8);
        *(uint4*)&wsp[1][4] = *(const uint4*)(ps8 + 12);
    }
    float2 pf = *(const float2*)&P[(size_t)i * 1024 + c0];
    float2 ps = *(const float2*)&P[(size_t)i * 1024 + 512 + c0];
    float2 bf2 = *(const float2*)&bfv[c0];
    float2 bs2 = *(const float2*)&bsv[c0];
    pf.x = fmaf(bf2.x, L2E, pf.x); pf.y = fmaf(bf2.y, L2E, pf.y);
    ps.x = fmaf(bs2.x, L2E, ps.x); ps.y = fmaf(bs2.y, L2E, ps.y);
    float acc0 = 0.f, acc1 = 0.f;
    int e0 = offs[i], e1 = offs[i + 1];
    __shared__ uint_t sEaP[32][8];
    __shared__ int sSrc[34];
    const ushort_t* Qbase = Qi + 4 * t;
    for (int base = e0; base < e1; base += 32) {
        int g = min(32, e1 - base);
        __syncthreads();
        if (t < 34) {
            int s = 0;
            if (t < g) s = srcArr[base + t];
            sSrc[t] = s;
        }
        {
            int j = t >> 3, k2 = t & 7;
            if (j < g) sEaP[j][k2] = eaP[(size_t)(base + j) * 8 + k2];
        }
        __syncthreads();
        uint2 q0 = *(const uint2*)(Qbase + ((size_t)sSrc[0] << 10));
        uint2 q1 = *(const uint2*)(Qbase + ((size_t)sSrc[1] << 10));
        for (int j = 0; j < g; j++) {
            uint2 qn = *(const uint2*)(Qbase + ((size_t)sSrc[j + 2] << 10));
            uint4 eA = *(const uint4*)&sEaP[j][0];
            uint4 eB = *(const uint4*)&sEaP[j][4];
            float gf0 = pf.x + bflo(q0.x), gf1 = pf.y + bfhi(q0.x);
            float gs0 = ps.x + bflo(q0.y), gs1 = ps.y + bfhi(q0.y);
            uint_t ek[8] = {eA.x, eA.y, eA.z, eA.w, eB.x, eB.y, eB.z, eB.w};
#pragma unroll
            for (int k = 0; k < 8; k++) {
                half2_t e2 = u2h(ek[k]);
                gf0 = __builtin_amdgcn_fdot2(e2, u2h(wfp[0][k]), gf0, false);
                gf1 = __builtin_amdgcn_fdot2(e2, u2h(wfp[1][k]), gf1, false);
                gs0 = __builtin_amdgcn_fdot2(e2, u2h(wsp[0][k]), gs0, false);
                gs1 = __builtin_amdgcn_fdot2(e2, u2h(wsp[1][k]), gs1, false);
            }
            float sg0 = __builtin_amdgcn_rcpf(1.f + fexp2(-gf0));
            float sg1 = __builtin_amdgcn_rcpf(1.f + fexp2(-gf1));
            float sp0 = fmaxf(gs0, 0.f) + flog2(1.f + fexp2(-fabsf(gs0)));
            float sp1 = fmaxf(gs1, 0.f) + flog2(1.f + fexp2(-fabsf(gs1)));
            acc0 = fmaf(sg0, sp0, acc0);
            acc1 = fmaf(sg1, sp1, acc1);
            q0 = q1; q1 = qn;
        }
    }
    acc0 *= LN2;
    acc1 *= LN2;
    size_t ib = (size_t)i * DIM;
    float2 mn = *(const float2*)&mean[c0];
    float2 vr = *(const float2*)&var[c0];
    float2 gm = *(const float2*)&gamma[c0];
    float2 bt = *(const float2*)&beta[c0];
    float2 xi = *(const float2*)&xin[ib + c0];
    float bn0 = (acc0 - mn.x) * rsqrtf(vr.x + BN_EPS) * gm.x + bt.x;
    float bn1 = (acc1 - mn.y) * rsqrtf(vr.y + BN_EPS) * gm.y + bt.y;
    float o0 = fmaxf(xi.x + bn0, 0.f);
    float o1 = fmaxf(xi.y + bn1, 0.f);
    if (xout) *(float2*)&xout[ib + c0] = make_float2(o0, o1);
    ushort_t h0 = f2bf(o0), h1 = f2bf(o1);
    *(uint_t*)(A2out + (size_t)i * 512 + c0) = (uint_t)h0 | ((uint_t)h1 << 16);
}

// ---------------- GCN aggregation (batch 32, bf16 in, bf16 out lda 256) ----------------
__global__ __launch_bounds__(128) void k_gcn_aggr(
    const ushort_t* __restrict__ h, const float* __restrict__ dinv,
    const float* __restrict__ bias,
    const int* __restrict__ offs, const int* __restrict__ srcArr,
    const float* __restrict__ dinvArr, ushort_t* __restrict__ A2out)
{
    int i = blockIdx.x;
    int t = threadIdx.x;
    int c0 = 2 * t;
    float acc0 = 0.f, acc1 = 0.f;
    int e0 = offs[i], e1 = offs[i + 1];
    __shared__ int sS[36];
    __shared__ float sD[36];
    for (int base = e0; base < e1; base += 32) {
        int g = min(32, e1 - base);
        __syncthreads();
        if (t < 36) {
            bool ok = (t < g);
            sS[t] = ok ? srcArr[base + t] : 0;
            sD[t] = ok ? dinvArr[base + t] : 0.f;
        }
        __syncthreads();
        uint_t q0 = *(const uint_t*)(h + (size_t)sS[0] * HDIM + c0);
        uint_t q1 = *(const uint_t*)(h + (size_t)sS[1] * HDIM + c0);
        uint_t q2 = *(const uint_t*)(h + (size_t)sS[2] * HDIM + c0);
        uint_t q3 = *(const uint_t*)(h + (size_t)sS[3] * HDIM + c0);
        for (int j = 0; j < g; j++) {
            uint_t qn = *(const uint_t*)(h + (size_t)sS[j + 4] * HDIM + c0);
            acc0 += sD[j] * bflo(q0);
            acc1 += sD[j] * bfhi(q0);
            q0 = q1; q1 = q2; q2 = q3; q3 = qn;
        }
    }
    float di = dinv[i];
    uint_t qi = *(const uint_t*)(h + (size_t)i * HDIM + c0);
    float2 b2 = *(const float2*)&bias[c0];
    float o0 = fmaxf(di * acc0 + di * di * bflo(qi) + b2.x, 0.f);
    float o1 = fmaxf(di * acc1 + di * di * bfhi(qi) + b2.y, 0.f);
    ushort_t h0 = f2bf(o0), h1 = f2bf(o1);
    *(uint_t*)(A2out + (size_t)i * 256 + c0) = (uint_t)h0 | ((uint_t)h1 << 16);
}

// ---------------- final dot ----------------
__global__ __launch_bounds__(256) void k_final(const float* __restrict__ hd,
                                               const float* __restrict__ w2,
                                               const float* __restrict__ b2,
                                               float* __restrict__ out) {
    int wave = threadIdx.x >> 6, lane = threadIdx.x & 63;
    int i = blockIdx.x * 4 + wave;
    if (i >= N_NODES) return;
    const float* r = hd + (size_t)i * DIM;
    float acc = 0.f;
#pragma unroll
    for (int q = 0; q < 8; q++) acc += r[lane + 64 * q] * w2[lane + 64 * q];
#pragma unroll
    for (int off = 32; off > 0; off >>= 1) acc += __shfl_down(acc, off, 64);
    if (lane == 0) out[i] = acc + b2[0];
}

// ---------------- launch ----------------
extern "C" void kernel_launch(void* const* d_in, const int* in_sizes, int n_in,
                              void* d_out, int out_size, void* d_ws, size_t ws_size,
                              hipStream_t stream) {
    (void)in_sizes; (void)n_in; (void)out_size; (void)ws_size;
    const float* x      = (const float*)d_in[0];
    const float* ea     = (const float*)d_in[1];
    const float* goal   = (const float*)d_in[2];
    const float* cgWf[2] = {(const float*)d_in[3],  (const float*)d_in[11]};
    const float* cgbf[2] = {(const float*)d_in[4],  (const float*)d_in[12]};
    const float* cgWs[2] = {(const float*)d_in[5],  (const float*)d_in[13]};
    const float* cgbs[2] = {(const float*)d_in[6],  (const float*)d_in[14]};
    const float* cggm[2] = {(const float*)d_in[7],  (const float*)d_in[15]};
    const float* cgbt[2] = {(const float*)d_in[8],  (const float*)d_in[16]};
    const float* cgmn[2] = {(const float*)d_in[9],  (const float*)d_in[17]};
    const float* cgvr[2] = {(const float*)d_in[10], (const float*)d_in[18]};
    const float* gcn3_W = (const float*)d_in[19];
    const float* gcn3_b = (const float*)d_in[20];
    const float* gcn4_W = (const float*)d_in[21];
    const float* gcn4_b = (const float*)d_in[22];
    const float* d1_W   = (const float*)d_in[23];
    const float* d1_b   = (const float*)d_in[24];
    const float* d2_W   = (const float*)d_in[25];
    const float* d2_b   = (const float*)d_in[26];
    const int*   eidx   = (const int*)d_in[27];
    const int*   srcv   = eidx;
    const int*   dstv   = eidx + N_EDGES;
    float* outp = (float*)d_out;

    // ---- workspace layout (~101 MB) ----
    char* w = (char*)d_ws;
    float*    Pbuf  = (float*)w;                      w += (size_t)N_NODES * 1024 * 4;
    ushort_t* Qbuf  = (ushort_t*)w;                   w += (size_t)N_NODES * 1024 * 2;
    float*    xB    = (float*)w;                      w += (size_t)N_NODES * 512 * 4;
    ushort_t* A2    = (ushort_t*)w;                   w += (size_t)N_NODES * 512 * 2;
    ushort_t* A3    = (ushort_t*)w;                   w += (size_t)N_NODES * 256 * 2;
    ushort_t* W2cg0 = (ushort_t*)w;                   w += (size_t)2048 * 512 * 2;
    ushort_t* W2cg1 = (ushort_t*)w;                   w += (size_t)2048 * 512 * 2;
    ushort_t* W2g3  = (ushort_t*)w;                   w += (size_t)256 * 512 * 2;
    ushort_t* W2g4  = (ushort_t*)w;                   w += (size_t)256 * 256 * 2;
    ushort_t* W2d1  = (ushort_t*)w;                   w += (size_t)512 * 256 * 2;
    uint_t*   eaP   = (uint_t*)w;                     w += (size_t)N_EDGES * 8 * 4;
    uint_t*   WEP   = (uint_t*)w;                     w += 16384 * 4;
    float*    cgv   = (float*)w;                      w += 512 * 4;
    int*      srcArr  = (int*)w;                      w += N_EDGES * 4;
    float*    dinvArr = (float*)w;                    w += N_EDGES * 4;
    int*      offs    = (int*)w;                      w += (N_NODES + 1) * 4;
    int*      cursor  = (int*)w;                      w += N_NODES * 4;
    float*    dinv    = (float*)w;                    w += N_NODES * 4;
    uint_t* WEPf[2] = {WEP, WEP + 8192};
    uint_t* WEPs[2] = {WEP + 4096, WEP + 12288};
    ushort_t* h3 = (ushort_t*)Pbuf;          // N x 256 bf16
    float*    hd = (float*)Qbuf;             // N x 512 f32

    // ---- prep ----
    k_cvtW<<<592, 256, 0, stream>>>(cgWf[0], cgWs[0], cgWf[1], cgWs[1],
                                    gcn3_W, gcn4_W, d1_W,
                                    W2cg0, W2cg1, W2g3, W2g4, W2d1);
    k_megaprep<<<MP_END, 256, 0, stream>>>(x, goal,
        cgWf[0], cgWs[0], cgWf[1], cgWs[1], d1_W, d1_b, A2, WEP, cgv);

    // ---- CSR build ----
    hipMemsetAsync(offs, 0, (N_NODES + 1) * sizeof(int), stream);
    hipMemsetAsync(cursor, 0, N_NODES * sizeof(int), stream);
    k_hist<<<(N_EDGES + 255) / 256, 256, 0, stream>>>(dstv, offs);
    k_scan<<<1, 1024, 0, stream>>>(offs, dinv);
    k_scatter<<<(N_EDGES + 255) / 256, 256, 0, stream>>>(srcv, dstv, ea, offs, dinv,
                                                         cursor, srcArr, dinvArr, eaP);

    // ---- CG layer 1 ----
    k_gemm3<<<79 * 16, 256, 0, stream>>>(A2, 512, N_NODES, W2cg0,
                                         Pbuf, Qbuf, nullptr, 1, 0, 79, 16);
    k_cg_aggr<<<N_NODES, 256, 0, stream>>>(x, Pbuf, Qbuf, WEPf[0], WEPs[0],
                                           cgbf[0], cgbs[0],
                                           cggm[0], cgbt[0], cgmn[0], cgvr[0],
                                           offs, srcArr, eaP, xB, A2);
    // ---- CG layer 2 (fp32 xout not needed downstream) ----
    k_gemm3<<<79 * 16, 256, 0, stream>>>(A2, 512, N_NODES, W2cg1,
                                         Pbuf, Qbuf, nullptr, 1, 0, 79, 16);
    k_cg_aggr<<<N_NODES, 256, 0, stream>>>(xB, Pbuf, Qbuf, WEPf[1], WEPs[1],
                                           cgbf[1], cgbs[1],
                                           cggm[1], cgbt[1], cgmn[1], cgvr[1],
                                           offs, srcArr, eaP, nullptr, A2);

    // ---- GCN 3: 512 -> 256 ----
    k_gemm64<<<157 * 2, 256, 0, stream>>>(A2, 512, N_NODES, W2g3,
                                          nullptr, h3, nullptr, 3, HDIM, 157, 2);
    k_gcn_aggr<<<N_NODES, 128, 0, stream>>>(h3, dinv, gcn3_b, offs, srcArr, dinvArr, A3);

    // ---- GCN 4: 256 -> 256 ----
    k_gemm64<<<157 * 2, 256, 0, stream>>>(A3, 256, N_NODES, W2g4,
                                          nullptr, h3, nullptr, 3, HDIM, 157, 2);
    k_gcn_aggr<<<N_NODES, 128, 0, stream>>>(h3, dinv, gcn4_b, offs, srcArr, dinvArr, A3);

    // ---- dense head ----
    k_gemm64<<<157 * 4, 256, 0, stream>>>(A3, 256, N_NODES, W2d1,
                                          hd, nullptr, cgv, 2, DIM, 157, 4);
    k_final<<<(N_NODES + 3) / 4, 256, 0, stream>>>(hd, d2_W, d2_b, outp);
}